// Round 1
// baseline (2384.297 us; speedup 1.0000x reference)
//
#include <hip/hip_runtime.h>
#include <math.h>

// Problem constants
#define BB   16
#define SS   512
#define CC   16
#define DD   512
#define HHH  8
#define DH   64
#define FF   2048
#define LL   2
#define NTOK (BB*SS)      // 8192
#define NG   (BB*HHH)     // 128 attention groups
#define GRP  (SS*DH)      // 32768 floats per attention group slab

// ---------------------------------------------------------------------------
// Kernel 1: embedding sum + time feature MLP + sinusoidal positional encoding
// out[tok,d] = sum_c emb[code[tok,c],d]*mask_code[tok,c] + bias_emb[d]
//            + (1-tanh((t*selW+selb)^2)) @ timeW + time_b + PE
// one block per token, 512 threads (one per d)
// ---------------------------------------------------------------------------
__global__ __launch_bounds__(512) void embed_kernel(
    const int*   __restrict__ event_code,  // [NTOK,16]
    const float* __restrict__ mask_code,   // [NTOK,16]
    const float* __restrict__ seq_time,    // [NTOK]
    const int*   __restrict__ input_len,   // [B]
    const float* __restrict__ emb,         // [V,512]
    const float* __restrict__ bias_emb,    // [512]
    const float* __restrict__ sel_W,       // [64]
    const float* __restrict__ sel_b,       // [64]
    const float* __restrict__ time_W,      // [64,512]
    const float* __restrict__ time_b,      // [512]
    float* __restrict__ out)               // [NTOK,512]
{
    const int tok = blockIdx.x;
    const int b   = tok >> 9;     // /512
    const int s   = tok & 511;
    const int d   = threadIdx.x;  // 0..511

    __shared__ float f[64];
    __shared__ int   codes[16];
    __shared__ float mcode[16];

    if (d < 64) {
        float t = seq_time[tok] * (1.0f / 7200.0f);
        float h = t * sel_W[d] + sel_b[d];
        f[d] = 1.0f - tanhf(h * h);
    }
    if (d >= 64 && d < 80) {
        int c = d - 64;
        codes[c] = event_code[tok * CC + c];
        mcode[c] = mask_code[tok * CC + c];
    }
    __syncthreads();

    float acc = bias_emb[d] + time_b[d];
    #pragma unroll
    for (int c = 0; c < CC; ++c)
        acc += emb[(long)codes[c] * DD + d] * mcode[c];
    #pragma unroll 8
    for (int j = 0; j < 64; ++j)
        acc += f[j] * time_W[j * DD + d];

    // positional encoding, gated by real length (index 0 of table = zeros)
    int pos = s + 1;
    if (pos <= input_len[b]) {
        int p = pos - 1;
        float e    = (float)(d & ~1) * (1.0f / 512.0f);
        float invf = exp2f(-13.287712379549449f * e);  // 10000^-e
        float ang  = (float)p * invf;
        acc += (d & 1) ? cosf(ang) : sinf(ang);
    }
    out[(long)tok * DD + d] = acc;
}

// ---------------------------------------------------------------------------
// Kernel 2: fp32 tiled GEMM  C[M,N] = A[M,K] @ W[K,N] + bias (+res) (relu?)
// BM=64, BN=128, BK=16; 256 threads; 4x8 micro-tile per thread
// ---------------------------------------------------------------------------
#define BM 64
#define BN 128
#define BK 16

template<bool RELU, bool RES>
__global__ __launch_bounds__(256) void gemm_kernel(
    const float* __restrict__ A,
    const float* __restrict__ W,
    const float* __restrict__ bias,
    const float* __restrict__ res,
    float* __restrict__ C,
    int M, int N, int K)
{
    __shared__ float As[BK][BM + 4];   // transposed A tile: As[k][m]
    __shared__ float Ws[BK][BN + 4];

    const int tid = threadIdx.x;
    const int tx  = tid & 15;   // 16 col-threads
    const int ty  = tid >> 4;   // 16 row-threads
    const int m0  = blockIdx.y * BM;
    const int n0  = blockIdx.x * BN;

    float acc[4][8];
    #pragma unroll
    for (int i = 0; i < 4; ++i)
        #pragma unroll
        for (int j = 0; j < 8; ++j) acc[i][j] = 0.f;

    for (int k0 = 0; k0 < K; k0 += BK) {
        // stage A tile (64x16), 1 float4 per thread, store transposed
        {
            int e = tid * 4;
            int r = e >> 4;      // 0..63
            int c = e & 15;      // multiple of 4
            float4 a4 = *(const float4*)(A + (long)(m0 + r) * K + k0 + c);
            As[c + 0][r] = a4.x; As[c + 1][r] = a4.y;
            As[c + 2][r] = a4.z; As[c + 3][r] = a4.w;
        }
        // stage W tile (16x128), 2 float4 per thread
        {
            int r = tid >> 4;          // 0..15
            int c = (tid & 15) * 8;    // 0..120
            *(float4*)&Ws[r][c]     = *(const float4*)(W + (long)(k0 + r) * N + n0 + c);
            *(float4*)&Ws[r][c + 4] = *(const float4*)(W + (long)(k0 + r) * N + n0 + c + 4);
        }
        __syncthreads();

        #pragma unroll
        for (int k = 0; k < BK; ++k) {
            float4 a4 = *(const float4*)&As[k][ty * 4];
            float4 w0 = *(const float4*)&Ws[k][tx * 8];
            float4 w1 = *(const float4*)&Ws[k][tx * 8 + 4];
            float a[4] = {a4.x, a4.y, a4.z, a4.w};
            float w[8] = {w0.x, w0.y, w0.z, w0.w, w1.x, w1.y, w1.z, w1.w};
            #pragma unroll
            for (int i = 0; i < 4; ++i)
                #pragma unroll
                for (int j = 0; j < 8; ++j)
                    acc[i][j] = fmaf(a[i], w[j], acc[i][j]);
        }
        __syncthreads();
    }

    // epilogue
    #pragma unroll
    for (int i = 0; i < 4; ++i) {
        int row = m0 + ty * 4 + i;
        long base = (long)row * N + n0 + tx * 8;
        #pragma unroll
        for (int jj = 0; jj < 8; jj += 4) {
            float4 v4;
            v4.x = acc[i][jj + 0] + bias[n0 + tx * 8 + jj + 0];
            v4.y = acc[i][jj + 1] + bias[n0 + tx * 8 + jj + 1];
            v4.z = acc[i][jj + 2] + bias[n0 + tx * 8 + jj + 2];
            v4.w = acc[i][jj + 3] + bias[n0 + tx * 8 + jj + 3];
            if (RES) {
                float4 r4 = *(const float4*)&res[base + jj];
                v4.x += r4.x; v4.y += r4.y; v4.z += r4.z; v4.w += r4.w;
            }
            if (RELU) {
                v4.x = fmaxf(v4.x, 0.f); v4.y = fmaxf(v4.y, 0.f);
                v4.z = fmaxf(v4.z, 0.f); v4.w = fmaxf(v4.w, 0.f);
            }
            *(float4*)&C[base + jj] = v4;
        }
    }
}

// ---------------------------------------------------------------------------
// Kernel 3: attention over 128 groups of [512 rows x 64 dims] (contiguous
// reinterpret of the reference's raw reshape). One thread = one query row,
// online softmax, K/V tiles of 64 staged in LDS. No padding mask (faithful
// to reference, which discards the masked scores).
// ---------------------------------------------------------------------------
__global__ __launch_bounds__(256) void attn_kernel(
    const float* __restrict__ Q,
    const float* __restrict__ K,
    const float* __restrict__ V,
    float* __restrict__ O)
{
    const int g    = blockIdx.x >> 1;
    const int half = blockIdx.x & 1;
    const int tid  = threadIdx.x;
    const int r    = half * 256 + tid;   // 0..511

    const float* qp = Q + (long)g * GRP + (long)r * DH;
    float q[DH];
    #pragma unroll
    for (int i = 0; i < 16; ++i)
        *(float4*)&q[i * 4] = *(const float4*)&qp[i * 4];

    float accv[DH];
    #pragma unroll
    for (int i = 0; i < DH; ++i) accv[i] = 0.f;
    float m = -1e30f, l = 0.f;
    const float scale = 0.125f;  // dh^-0.5

    __shared__ float Ks[64][64];
    __shared__ float Vs[64][64];

    for (int kt = 0; kt < 8; ++kt) {
        __syncthreads();
        const float* kbase = K + (long)g * GRP + (long)kt * 64 * 64;
        const float* vbase = V + (long)g * GRP + (long)kt * 64 * 64;
        #pragma unroll
        for (int i = 0; i < 4; ++i) {
            int e  = (tid + i * 256) * 4;
            int rr = e >> 6, cc = e & 63;
            *(float4*)&Ks[rr][cc] = *(const float4*)&kbase[e];
            *(float4*)&Vs[rr][cc] = *(const float4*)&vbase[e];
        }
        __syncthreads();

        for (int kk = 0; kk < 64; ++kk) {
            float s0 = 0.f, s1 = 0.f, s2 = 0.f, s3 = 0.f;
            #pragma unroll
            for (int d4 = 0; d4 < DH; d4 += 4) {
                s0 = fmaf(q[d4 + 0], Ks[kk][d4 + 0], s0);
                s1 = fmaf(q[d4 + 1], Ks[kk][d4 + 1], s1);
                s2 = fmaf(q[d4 + 2], Ks[kk][d4 + 2], s2);
                s3 = fmaf(q[d4 + 3], Ks[kk][d4 + 3], s3);
            }
            float s = ((s0 + s1) + (s2 + s3)) * scale;
            if (s <= m) {
                float p = __expf(s - m);
                l += p;
                #pragma unroll
                for (int d = 0; d < DH; ++d)
                    accv[d] = fmaf(p, Vs[kk][d], accv[d]);
            } else {
                float corr = __expf(m - s);   // first iter: exp(-inf)=0
                m = s;
                l = l * corr + 1.0f;
                #pragma unroll
                for (int d = 0; d < DH; ++d)
                    accv[d] = fmaf(accv[d], corr, Vs[kk][d]);
            }
        }
    }

    float inv = 1.0f / l;
    float* op = O + (long)g * GRP + (long)r * DH;
    #pragma unroll
    for (int i = 0; i < 16; ++i) {
        float4 o4;
        o4.x = accv[i * 4 + 0] * inv; o4.y = accv[i * 4 + 1] * inv;
        o4.z = accv[i * 4 + 2] * inv; o4.w = accv[i * 4 + 3] * inv;
        *(float4*)&op[i * 4] = o4;
    }
}

// ---------------------------------------------------------------------------
// Kernel 4: LayerNorm over D=512 (two-pass, matches reference mean/var form)
// one block per row, 256 threads, 2 elems each
// ---------------------------------------------------------------------------
__global__ __launch_bounds__(256) void ln_kernel(
    const float* __restrict__ X,
    const float* __restrict__ gam,
    const float* __restrict__ bet,
    float* __restrict__ Y,
    float eps)
{
    const int row = blockIdx.x;
    const int tid = threadIdx.x;
    const float* x = X + (long)row * DD;

    float x0 = x[tid], x1 = x[tid + 256];
    __shared__ float ws4[4];
    const int wid = tid >> 6, lane = tid & 63;

    // mean
    float sum = x0 + x1;
    #pragma unroll
    for (int off = 32; off > 0; off >>= 1) sum += __shfl_down(sum, off, 64);
    if (lane == 0) ws4[wid] = sum;
    __syncthreads();
    float mean = (ws4[0] + ws4[1] + ws4[2] + ws4[3]) * (1.0f / 512.0f);
    __syncthreads();

    // variance (two-pass like reference)
    float d0 = x0 - mean, d1 = x1 - mean;
    float s2 = d0 * d0 + d1 * d1;
    #pragma unroll
    for (int off = 32; off > 0; off >>= 1) s2 += __shfl_down(s2, off, 64);
    if (lane == 0) ws4[wid] = s2;
    __syncthreads();
    float var = (ws4[0] + ws4[1] + ws4[2] + ws4[3]) * (1.0f / 512.0f);
    float inv = rsqrtf(var + eps);

    Y[(long)row * DD + tid]       = d0 * inv * gam[tid]       + bet[tid];
    Y[(long)row * DD + tid + 256] = d1 * inv * gam[tid + 256] + bet[tid + 256];
}

// ---------------------------------------------------------------------------
extern "C" void kernel_launch(void* const* d_in, const int* in_sizes, int n_in,
                              void* d_out, int out_size, void* d_ws, size_t ws_size,
                              hipStream_t stream)
{
    const int*   event_code = (const int*)  d_in[0];
    // d_in[1] = mask        : unused by reference
    const float* mask_code  = (const float*)d_in[2];
    const float* seq_time   = (const float*)d_in[3];
    // d_in[4], d_in[5]      : event_failure_* unused by reference
    const int*   input_len  = (const int*)  d_in[6];
    const float* emb        = (const float*)d_in[7];
    const float* bias_emb   = (const float*)d_in[8];
    const float* sel_W      = (const float*)d_in[9];
    const float* sel_b      = (const float*)d_in[10];
    const float* time_W     = (const float*)d_in[11];
    const float* time_b     = (const float*)d_in[12];
    const float* Wq  = (const float*)d_in[13];
    const float* bq  = (const float*)d_in[14];
    const float* Wk  = (const float*)d_in[15];
    const float* bk  = (const float*)d_in[16];
    const float* Wv  = (const float*)d_in[17];
    const float* bv  = (const float*)d_in[18];
    const float* Wo  = (const float*)d_in[19];
    const float* bo  = (const float*)d_in[20];
    const float* ln1g = (const float*)d_in[21];
    const float* ln1b = (const float*)d_in[22];
    const float* W1  = (const float*)d_in[23];
    const float* b1  = (const float*)d_in[24];
    const float* W2  = (const float*)d_in[25];
    const float* b2  = (const float*)d_in[26];
    const float* ln2g = (const float*)d_in[27];
    const float* ln2b = (const float*)d_in[28];

    // workspace layout (floats): x, y, q, k, v each ND; h = 4*ND (FFN hidden,
    // doubles as attention ctx). Total 9*ND = 151 MB.
    float* ws = (float*)d_ws;
    const long ND = (long)NTOK * DD;
    float* x = ws;
    float* y = ws + ND;
    float* q = ws + 2 * ND;
    float* k = ws + 3 * ND;
    float* v = ws + 4 * ND;
    float* h = ws + 5 * ND;

    embed_kernel<<<NTOK, 512, 0, stream>>>(event_code, mask_code, seq_time, input_len,
                                           emb, bias_emb, sel_W, sel_b, time_W, time_b, x);

    const dim3 g512(DD / BN, NTOK / BM);   // (4,128)
    const dim3 gFF(FF / BN, NTOK / BM);    // (16,128)

    for (int l = 0; l < LL; ++l) {
        const float* Wq_l = Wq + (long)l * DD * DD;
        const float* Wk_l = Wk + (long)l * DD * DD;
        const float* Wv_l = Wv + (long)l * DD * DD;
        const float* Wo_l = Wo + (long)l * DD * DD;
        const float* W1_l = W1 + (long)l * DD * FF;
        const float* W2_l = W2 + (long)l * FF * DD;

        gemm_kernel<false, false><<<g512, 256, 0, stream>>>(x, Wq_l, bq + l * DD, nullptr, q, NTOK, DD, DD);
        gemm_kernel<false, false><<<g512, 256, 0, stream>>>(x, Wk_l, bk + l * DD, nullptr, k, NTOK, DD, DD);
        gemm_kernel<false, false><<<g512, 256, 0, stream>>>(x, Wv_l, bv + l * DD, nullptr, v, NTOK, DD, DD);

        attn_kernel<<<NG * 2, 256, 0, stream>>>(q, k, v, h);

        // y = x + ctx@Wo + bo ; then LN1 (eps 1e-3) in place
        gemm_kernel<false, true><<<g512, 256, 0, stream>>>(h, Wo_l, bo + l * DD, x, y, NTOK, DD, DD);
        ln_kernel<<<NTOK, 256, 0, stream>>>(y, ln1g + l * DD, ln1b + l * DD, y, 1e-3f);

        // h = relu(y@W1 + b1) ; x = y + h@W2 + b2 ; LN2 (eps 1e-6) in place
        gemm_kernel<true, false><<<gFF, 256, 0, stream>>>(y, W1_l, b1 + l * FF, nullptr, h, NTOK, FF, DD);
        gemm_kernel<false, true><<<g512, 256, 0, stream>>>(h, W2_l, b2 + l * DD, y, x, NTOK, DD, FF);
        ln_kernel<<<NTOK, 256, 0, stream>>>(x, ln2g + l * DD, ln2b + l * DD, x, 1e-6f);
    }

    hipMemcpyAsync(d_out, x, ND * sizeof(float), hipMemcpyDeviceToDevice, stream);
}

// Round 2
// 2005.836 us; speedup vs baseline: 1.1887x; 1.1887x over previous
//
#include <hip/hip_runtime.h>
#include <math.h>

// Problem constants
#define BB   16
#define SS   512
#define CC   16
#define DD   512
#define HHH  8
#define DH   64
#define FF   2048
#define LL   2
#define NTOK (BB*SS)      // 8192
#define NG   (BB*HHH)     // 128 attention groups
#define GRP  (SS*DH)      // 32768 floats per attention group slab

// ---------------------------------------------------------------------------
// Kernel 1: embedding sum + time feature MLP + sinusoidal positional encoding
// ---------------------------------------------------------------------------
__global__ __launch_bounds__(512) void embed_kernel(
    const int*   __restrict__ event_code,  // [NTOK,16]
    const float* __restrict__ mask_code,   // [NTOK,16]
    const float* __restrict__ seq_time,    // [NTOK]
    const int*   __restrict__ input_len,   // [B]
    const float* __restrict__ emb,         // [V,512]
    const float* __restrict__ bias_emb,    // [512]
    const float* __restrict__ sel_W,       // [64]
    const float* __restrict__ sel_b,       // [64]
    const float* __restrict__ time_W,      // [64,512]
    const float* __restrict__ time_b,      // [512]
    float* __restrict__ out)               // [NTOK,512]
{
    const int tok = blockIdx.x;
    const int b   = tok >> 9;     // /512
    const int s   = tok & 511;
    const int d   = threadIdx.x;  // 0..511

    __shared__ float f[64];
    __shared__ int   codes[16];
    __shared__ float mcode[16];

    if (d < 64) {
        float t = seq_time[tok] * (1.0f / 7200.0f);
        float h = t * sel_W[d] + sel_b[d];
        f[d] = 1.0f - tanhf(h * h);
    }
    if (d >= 64 && d < 80) {
        int c = d - 64;
        codes[c] = event_code[tok * CC + c];
        mcode[c] = mask_code[tok * CC + c];
    }
    __syncthreads();

    float acc = bias_emb[d] + time_b[d];
    #pragma unroll
    for (int c = 0; c < CC; ++c)
        acc += emb[(long)codes[c] * DD + d] * mcode[c];
    #pragma unroll 8
    for (int j = 0; j < 64; ++j)
        acc += f[j] * time_W[j * DD + d];

    // positional encoding, gated by real length (index 0 of table = zeros)
    int pos = s + 1;
    if (pos <= input_len[b]) {
        int p = pos - 1;
        float e    = (float)(d & ~1) * (1.0f / 512.0f);
        float invf = exp2f(-13.287712379549449f * e);  // 10000^-e
        float ang  = (float)p * invf;
        acc += (d & 1) ? cosf(ang) : sinf(ang);
    }
    out[(long)tok * DD + d] = acc;
}

// ---------------------------------------------------------------------------
// Kernel 2a: fp32 tiled GEMM  C[M,N] = A[M,K] @ W[K,N] + bias (+res) (relu?)
// BM=64, BN=128, BK=16; 256 threads; 4x8 micro-tile (used for N=512 GEMMs)
// ---------------------------------------------------------------------------
#define BM 64
#define BN 128
#define BK 16

template<bool RELU, bool RES>
__global__ __launch_bounds__(256) void gemm_kernel(
    const float* __restrict__ A,
    const float* __restrict__ W,
    const float* __restrict__ bias,
    const float* __restrict__ res,
    float* __restrict__ C,
    int M, int N, int K)
{
    __shared__ float As[BK][BM + 4];   // transposed A tile: As[k][m]
    __shared__ float Ws[BK][BN + 4];

    const int tid = threadIdx.x;
    const int tx  = tid & 15;   // 16 col-threads
    const int ty  = tid >> 4;   // 16 row-threads
    const int m0  = blockIdx.y * BM;
    const int n0  = blockIdx.x * BN;

    float acc[4][8];
    #pragma unroll
    for (int i = 0; i < 4; ++i)
        #pragma unroll
        for (int j = 0; j < 8; ++j) acc[i][j] = 0.f;

    for (int k0 = 0; k0 < K; k0 += BK) {
        {
            int e = tid * 4;
            int r = e >> 4;      // 0..63
            int c = e & 15;      // multiple of 4
            float4 a4 = *(const float4*)(A + (long)(m0 + r) * K + k0 + c);
            As[c + 0][r] = a4.x; As[c + 1][r] = a4.y;
            As[c + 2][r] = a4.z; As[c + 3][r] = a4.w;
        }
        {
            int r = tid >> 4;          // 0..15
            int c = (tid & 15) * 8;    // 0..120
            *(float4*)&Ws[r][c]     = *(const float4*)(W + (long)(k0 + r) * N + n0 + c);
            *(float4*)&Ws[r][c + 4] = *(const float4*)(W + (long)(k0 + r) * N + n0 + c + 4);
        }
        __syncthreads();

        #pragma unroll
        for (int k = 0; k < BK; ++k) {
            float4 a4 = *(const float4*)&As[k][ty * 4];
            float4 w0 = *(const float4*)&Ws[k][tx * 8];
            float4 w1 = *(const float4*)&Ws[k][tx * 8 + 4];
            float a[4] = {a4.x, a4.y, a4.z, a4.w};
            float w[8] = {w0.x, w0.y, w0.z, w0.w, w1.x, w1.y, w1.z, w1.w};
            #pragma unroll
            for (int i = 0; i < 4; ++i)
                #pragma unroll
                for (int j = 0; j < 8; ++j)
                    acc[i][j] = fmaf(a[i], w[j], acc[i][j]);
        }
        __syncthreads();
    }

    #pragma unroll
    for (int i = 0; i < 4; ++i) {
        int row = m0 + ty * 4 + i;
        long base = (long)row * N + n0 + tx * 8;
        #pragma unroll
        for (int jj = 0; jj < 8; jj += 4) {
            float4 v4;
            v4.x = acc[i][jj + 0] + bias[n0 + tx * 8 + jj + 0];
            v4.y = acc[i][jj + 1] + bias[n0 + tx * 8 + jj + 1];
            v4.z = acc[i][jj + 2] + bias[n0 + tx * 8 + jj + 2];
            v4.w = acc[i][jj + 3] + bias[n0 + tx * 8 + jj + 3];
            if (RES) {
                float4 r4 = *(const float4*)&res[base + jj];
                v4.x += r4.x; v4.y += r4.y; v4.z += r4.z; v4.w += r4.w;
            }
            if (RELU) {
                v4.x = fmaxf(v4.x, 0.f); v4.y = fmaxf(v4.y, 0.f);
                v4.z = fmaxf(v4.z, 0.f); v4.w = fmaxf(v4.w, 0.f);
            }
            *(float4*)&C[base + jj] = v4;
        }
    }
}

// ---------------------------------------------------------------------------
// Kernel 2b: fp32 GEMM, BM=128 BN=128 BK=16, 8x8 micro-tile (for W1, N=2048)
// better FMA:LDS-read ratio (64 fma : 4 b128 reads per k-step)
// ---------------------------------------------------------------------------
template<bool RELU>
__global__ __launch_bounds__(256) void gemm128_kernel(
    const float* __restrict__ A,
    const float* __restrict__ W,
    const float* __restrict__ bias,
    float* __restrict__ C,
    int M, int N, int K)
{
    __shared__ float As[BK][128 + 4];
    __shared__ float Ws[BK][128 + 4];

    const int tid = threadIdx.x;
    const int tx  = tid & 15;   // col group
    const int ty  = tid >> 4;   // row group
    const int m0  = blockIdx.y * 128;
    const int n0  = blockIdx.x * 128;

    float acc[8][8];
    #pragma unroll
    for (int i = 0; i < 8; ++i)
        #pragma unroll
        for (int j = 0; j < 8; ++j) acc[i][j] = 0.f;

    for (int k0 = 0; k0 < K; k0 += BK) {
        // A tile: 128x16, 8 floats/thread, stored transposed
        {
            int r = tid >> 1;            // 0..127
            int c = (tid & 1) * 8;       // 0 or 8
            float4 a0 = *(const float4*)(A + (long)(m0 + r) * K + k0 + c);
            float4 a1 = *(const float4*)(A + (long)(m0 + r) * K + k0 + c + 4);
            As[c + 0][r] = a0.x; As[c + 1][r] = a0.y; As[c + 2][r] = a0.z; As[c + 3][r] = a0.w;
            As[c + 4][r] = a1.x; As[c + 5][r] = a1.y; As[c + 6][r] = a1.z; As[c + 7][r] = a1.w;
        }
        // W tile: 16x128, 8 floats/thread
        {
            int r = tid >> 4;            // 0..15
            int c = (tid & 15) * 8;      // 0..120
            *(float4*)&Ws[r][c]     = *(const float4*)(W + (long)(k0 + r) * N + n0 + c);
            *(float4*)&Ws[r][c + 4] = *(const float4*)(W + (long)(k0 + r) * N + n0 + c + 4);
        }
        __syncthreads();

        #pragma unroll
        for (int k = 0; k < BK; ++k) {
            float a[8], w[8];
            *(float4*)&a[0] = *(const float4*)&As[k][ty * 8];
            *(float4*)&a[4] = *(const float4*)&As[k][ty * 8 + 4];
            *(float4*)&w[0] = *(const float4*)&Ws[k][tx * 8];
            *(float4*)&w[4] = *(const float4*)&Ws[k][tx * 8 + 4];
            #pragma unroll
            for (int i = 0; i < 8; ++i)
                #pragma unroll
                for (int j = 0; j < 8; ++j)
                    acc[i][j] = fmaf(a[i], w[j], acc[i][j]);
        }
        __syncthreads();
    }

    #pragma unroll
    for (int i = 0; i < 8; ++i) {
        int row = m0 + ty * 8 + i;
        long base = (long)row * N + n0 + tx * 8;
        #pragma unroll
        for (int jj = 0; jj < 8; jj += 4) {
            float4 v4;
            v4.x = acc[i][jj + 0] + bias[n0 + tx * 8 + jj + 0];
            v4.y = acc[i][jj + 1] + bias[n0 + tx * 8 + jj + 1];
            v4.z = acc[i][jj + 2] + bias[n0 + tx * 8 + jj + 2];
            v4.w = acc[i][jj + 3] + bias[n0 + tx * 8 + jj + 3];
            if (RELU) {
                v4.x = fmaxf(v4.x, 0.f); v4.y = fmaxf(v4.y, 0.f);
                v4.z = fmaxf(v4.z, 0.f); v4.w = fmaxf(v4.w, 0.f);
            }
            *(float4*)&C[base + jj] = v4;
        }
    }
}

// ---------------------------------------------------------------------------
// Kernel 3: attention, 4 threads per query (16 dims each), 64 queries/block.
// Grid = 128 groups x 8 query-tiles = 1024 blocks -> 4 blocks/CU (vs 1 before).
// Defer-threshold online softmax (rescale only when max grows > 8; scores are
// O(1) here so this fires only at init). Faithful: no padding mask applied.
// ---------------------------------------------------------------------------
__global__ __launch_bounds__(256) void attn_kernel(
    const float* __restrict__ Q,
    const float* __restrict__ K,
    const float* __restrict__ V,
    float* __restrict__ O)
{
    const int g     = blockIdx.x >> 3;   // group 0..127
    const int qt    = blockIdx.x & 7;    // query tile 0..7
    const int tid   = threadIdx.x;
    const int qi    = tid >> 2;          // query within tile 0..63
    const int quart = tid & 3;           // dim quarter 0..3
    const int r     = qt * 64 + qi;      // query row 0..511

    __shared__ float4 Ks[64][16];        // 64 keys x 64 dims
    __shared__ float4 Vs[64][16];

    const float4* qp = (const float4*)(Q + (long)g * GRP + (long)r * DH) + quart * 4;
    float4 q0 = qp[0], q1 = qp[1], q2 = qp[2], q3 = qp[3];

    float4 a0 = {0,0,0,0}, a1 = {0,0,0,0}, a2 = {0,0,0,0}, a3 = {0,0,0,0};
    float m = -1e30f, l = 0.f;

    for (int kt = 0; kt < 8; ++kt) {
        __syncthreads();
        const float4* kb = (const float4*)(K + (long)g * GRP + (long)kt * 4096);
        const float4* vb = (const float4*)(V + (long)g * GRP + (long)kt * 4096);
        float4* ksl = (float4*)Ks;
        float4* vsl = (float4*)Vs;
        #pragma unroll
        for (int j = 0; j < 4; ++j) {
            ksl[tid + j * 256] = kb[tid + j * 256];
            vsl[tid + j * 256] = vb[tid + j * 256];
        }
        __syncthreads();

        #pragma unroll 4
        for (int kk = 0; kk < 64; ++kk) {
            float4 k0 = Ks[kk][quart * 4 + 0];
            float4 k1 = Ks[kk][quart * 4 + 1];
            float4 k2 = Ks[kk][quart * 4 + 2];
            float4 k3 = Ks[kk][quart * 4 + 3];
            float s0 = fmaf(q0.x, k0.x, fmaf(q0.y, k0.y, fmaf(q0.z, k0.z, q0.w * k0.w)));
            float s1 = fmaf(q1.x, k1.x, fmaf(q1.y, k1.y, fmaf(q1.z, k1.z, q1.w * k1.w)));
            float s2 = fmaf(q2.x, k2.x, fmaf(q2.y, k2.y, fmaf(q2.z, k2.z, q2.w * k2.w)));
            float s3 = fmaf(q3.x, k3.x, fmaf(q3.y, k3.y, fmaf(q3.z, k3.z, q3.w * k3.w)));
            float s = (s0 + s1) + (s2 + s3);
            s += __shfl_xor(s, 1);
            s += __shfl_xor(s, 2);
            s *= 0.125f;                       // dh^-0.5

            if (s - m > 8.0f) {                // rare: rescale (fires at init only)
                float corr = __expf(m - s);    // exp(-inf)=0 on first key
                l *= corr;
                a0.x *= corr; a0.y *= corr; a0.z *= corr; a0.w *= corr;
                a1.x *= corr; a1.y *= corr; a1.z *= corr; a1.w *= corr;
                a2.x *= corr; a2.y *= corr; a2.z *= corr; a2.w *= corr;
                a3.x *= corr; a3.y *= corr; a3.z *= corr; a3.w *= corr;
                m = s;
            }
            float p = __expf(s - m);
            l += p;
            float4 v0 = Vs[kk][quart * 4 + 0];
            float4 v1 = Vs[kk][quart * 4 + 1];
            float4 v2 = Vs[kk][quart * 4 + 2];
            float4 v3 = Vs[kk][quart * 4 + 3];
            a0.x = fmaf(p, v0.x, a0.x); a0.y = fmaf(p, v0.y, a0.y);
            a0.z = fmaf(p, v0.z, a0.z); a0.w = fmaf(p, v0.w, a0.w);
            a1.x = fmaf(p, v1.x, a1.x); a1.y = fmaf(p, v1.y, a1.y);
            a1.z = fmaf(p, v1.z, a1.z); a1.w = fmaf(p, v1.w, a1.w);
            a2.x = fmaf(p, v2.x, a2.x); a2.y = fmaf(p, v2.y, a2.y);
            a2.z = fmaf(p, v2.z, a2.z); a2.w = fmaf(p, v2.w, a2.w);
            a3.x = fmaf(p, v3.x, a3.x); a3.y = fmaf(p, v3.y, a3.y);
            a3.z = fmaf(p, v3.z, a3.z); a3.w = fmaf(p, v3.w, a3.w);
        }
    }

    float inv = 1.0f / l;
    float4* op = (float4*)(O + (long)g * GRP + (long)r * DH) + quart * 4;
    op[0] = make_float4(a0.x * inv, a0.y * inv, a0.z * inv, a0.w * inv);
    op[1] = make_float4(a1.x * inv, a1.y * inv, a1.z * inv, a1.w * inv);
    op[2] = make_float4(a2.x * inv, a2.y * inv, a2.z * inv, a2.w * inv);
    op[3] = make_float4(a3.x * inv, a3.y * inv, a3.z * inv, a3.w * inv);
}

// ---------------------------------------------------------------------------
// Kernel 4: LayerNorm over D=512 (two-pass, matches reference mean/var form)
// ---------------------------------------------------------------------------
__global__ __launch_bounds__(256) void ln_kernel(
    const float* __restrict__ X,
    const float* __restrict__ gam,
    const float* __restrict__ bet,
    float* __restrict__ Y,
    float eps)
{
    const int row = blockIdx.x;
    const int tid = threadIdx.x;
    const float* x = X + (long)row * DD;

    float x0 = x[tid], x1 = x[tid + 256];
    __shared__ float ws4[4];
    const int wid = tid >> 6, lane = tid & 63;

    float sum = x0 + x1;
    #pragma unroll
    for (int off = 32; off > 0; off >>= 1) sum += __shfl_down(sum, off, 64);
    if (lane == 0) ws4[wid] = sum;
    __syncthreads();
    float mean = (ws4[0] + ws4[1] + ws4[2] + ws4[3]) * (1.0f / 512.0f);
    __syncthreads();

    float d0 = x0 - mean, d1 = x1 - mean;
    float s2 = d0 * d0 + d1 * d1;
    #pragma unroll
    for (int off = 32; off > 0; off >>= 1) s2 += __shfl_down(s2, off, 64);
    if (lane == 0) ws4[wid] = s2;
    __syncthreads();
    float var = (ws4[0] + ws4[1] + ws4[2] + ws4[3]) * (1.0f / 512.0f);
    float inv = rsqrtf(var + eps);

    Y[(long)row * DD + tid]       = d0 * inv * gam[tid]       + bet[tid];
    Y[(long)row * DD + tid + 256] = d1 * inv * gam[tid + 256] + bet[tid + 256];
}

// ---------------------------------------------------------------------------
extern "C" void kernel_launch(void* const* d_in, const int* in_sizes, int n_in,
                              void* d_out, int out_size, void* d_ws, size_t ws_size,
                              hipStream_t stream)
{
    const int*   event_code = (const int*)  d_in[0];
    const float* mask_code  = (const float*)d_in[2];
    const float* seq_time   = (const float*)d_in[3];
    const int*   input_len  = (const int*)  d_in[6];
    const float* emb        = (const float*)d_in[7];
    const float* bias_emb   = (const float*)d_in[8];
    const float* sel_W      = (const float*)d_in[9];
    const float* sel_b      = (const float*)d_in[10];
    const float* time_W     = (const float*)d_in[11];
    const float* time_b     = (const float*)d_in[12];
    const float* Wq  = (const float*)d_in[13];
    const float* bq  = (const float*)d_in[14];
    const float* Wk  = (const float*)d_in[15];
    const float* bk  = (const float*)d_in[16];
    const float* Wv  = (const float*)d_in[17];
    const float* bv  = (const float*)d_in[18];
    const float* Wo  = (const float*)d_in[19];
    const float* bo  = (const float*)d_in[20];
    const float* ln1g = (const float*)d_in[21];
    const float* ln1b = (const float*)d_in[22];
    const float* W1  = (const float*)d_in[23];
    const float* b1  = (const float*)d_in[24];
    const float* W2  = (const float*)d_in[25];
    const float* b2  = (const float*)d_in[26];
    const float* ln2g = (const float*)d_in[27];
    const float* ln2b = (const float*)d_in[28];

    float* ws = (float*)d_ws;
    const long ND = (long)NTOK * DD;
    float* x = ws;
    float* y = ws + ND;
    float* q = ws + 2 * ND;
    float* k = ws + 3 * ND;
    float* v = ws + 4 * ND;
    float* h = ws + 5 * ND;   // FFN hidden [NTOK,2048]; also attention ctx

    embed_kernel<<<NTOK, 512, 0, stream>>>(event_code, mask_code, seq_time, input_len,
                                           emb, bias_emb, sel_W, sel_b, time_W, time_b, x);

    const dim3 g512(DD / BN, NTOK / BM);     // (4,128)
    const dim3 gW1(FF / 128, NTOK / 128);    // (16,64)

    for (int l = 0; l < LL; ++l) {
        const float* Wq_l = Wq + (long)l * DD * DD;
        const float* Wk_l = Wk + (long)l * DD * DD;
        const float* Wv_l = Wv + (long)l * DD * DD;
        const float* Wo_l = Wo + (long)l * DD * DD;
        const float* W1_l = W1 + (long)l * DD * FF;
        const float* W2_l = W2 + (long)l * FF * DD;

        gemm_kernel<false, false><<<g512, 256, 0, stream>>>(x, Wq_l, bq + l * DD, nullptr, q, NTOK, DD, DD);
        gemm_kernel<false, false><<<g512, 256, 0, stream>>>(x, Wk_l, bk + l * DD, nullptr, k, NTOK, DD, DD);
        gemm_kernel<false, false><<<g512, 256, 0, stream>>>(x, Wv_l, bv + l * DD, nullptr, v, NTOK, DD, DD);

        attn_kernel<<<NG * 8, 256, 0, stream>>>(q, k, v, h);

        // y = x + ctx@Wo + bo ; LN1 (eps 1e-3)
        gemm_kernel<false, true><<<g512, 256, 0, stream>>>(h, Wo_l, bo + l * DD, x, y, NTOK, DD, DD);
        ln_kernel<<<NTOK, 256, 0, stream>>>(y, ln1g + l * DD, ln1b + l * DD, y, 1e-3f);

        // h = relu(y@W1 + b1) ; x = y + h@W2 + b2 ; LN2 (eps 1e-6)
        gemm128_kernel<true><<<gW1, 256, 0, stream>>>(y, W1_l, b1 + l * FF, h, NTOK, FF, DD);
        gemm_kernel<false, true><<<g512, 256, 0, stream>>>(h, W2_l, b2 + l * DD, y, x, NTOK, DD, FF);
        ln_kernel<<<NTOK, 256, 0, stream>>>(x, ln2g + l * DD, ln2b + l * DD, x, 1e-6f);
    }

    hipMemcpyAsync(d_out, x, ND * sizeof(float), hipMemcpyDeviceToDevice, stream);
}

// Round 3
// 1458.927 us; speedup vs baseline: 1.6343x; 1.3749x over previous
//
#include <hip/hip_runtime.h>
#include <math.h>

// Problem constants
#define BB   16
#define SS   512
#define CC   16
#define DD   512
#define DH   64
#define FF   2048
#define LL   2
#define NTOK (BB*SS)      // 8192
#define NG   (BB*8)       // 128 attention groups
#define GRP  (SS*DH)      // 32768 floats per attention group slab

typedef unsigned short u16;
typedef __attribute__((ext_vector_type(8))) short bf16x8;
typedef __attribute__((ext_vector_type(4))) float f32x4;

__device__ __forceinline__ u16 f2bf(float x) {
    unsigned u = __float_as_uint(x);
    u = (u + 0x7fffu + ((u >> 16) & 1u)) >> 16;
    return (u16)u;
}
__device__ __forceinline__ float bf2f(u16 h) {
    return __uint_as_float(((unsigned)h) << 16);
}
__device__ __forceinline__ void gload16(const void* g, void* l) {
    __builtin_amdgcn_global_load_lds((const __attribute__((address_space(1))) void*)g,
                                     (__attribute__((address_space(3))) void*)l, 16, 0, 0);
}

// ---------------------------------------------------------------------------
// Kernel 0: weight transpose + fp32 -> bf16 hi/lo split.  W[K][N] -> Wt[N][K]
// grid (N/32, K/32, L), 256 threads
// ---------------------------------------------------------------------------
__global__ __launch_bounds__(256) void cvt_weight(
    const float* __restrict__ W, u16* __restrict__ Th, u16* __restrict__ Tl,
    int K, int N)
{
    const long moff = (long)blockIdx.z * K * N;
    W  += moff; Th += moff; Tl += moff;
    const int n0 = blockIdx.x * 32, k0 = blockIdx.y * 32;
    __shared__ float T[32][33];
    const int t = threadIdx.x;

    {   // load 32x32 tile coalesced, store transposed T[n][k]
        const int lk = t >> 3, ln4 = (t & 7) * 4;
        float4 w4 = *(const float4*)&W[(long)(k0 + lk) * N + n0 + ln4];
        T[ln4 + 0][lk] = w4.x; T[ln4 + 1][lk] = w4.y;
        T[ln4 + 2][lk] = w4.z; T[ln4 + 3][lk] = w4.w;
    }
    __syncthreads();
    {   // write out k-contiguous, split hi/lo
        const int nn = t >> 3, kq = (t & 7) * 4;
        float v0 = T[nn][kq + 0], v1 = T[nn][kq + 1];
        float v2 = T[nn][kq + 2], v3 = T[nn][kq + 3];
        ushort4 hh, ll;
        hh.x = f2bf(v0); ll.x = f2bf(v0 - bf2f(hh.x));
        hh.y = f2bf(v1); ll.y = f2bf(v1 - bf2f(hh.y));
        hh.z = f2bf(v2); ll.z = f2bf(v2 - bf2f(hh.z));
        hh.w = f2bf(v3); ll.w = f2bf(v3 - bf2f(hh.w));
        long o = (long)(n0 + nn) * K + k0 + kq;
        *(ushort4*)&Th[o] = hh;
        *(ushort4*)&Tl[o] = ll;
    }
}

// ---------------------------------------------------------------------------
// Kernel 1: embedding sum + time MLP + positional encoding; emits fp32 + hi/lo
// ---------------------------------------------------------------------------
__global__ __launch_bounds__(512) void embed_kernel(
    const int*   __restrict__ event_code,
    const float* __restrict__ mask_code,
    const float* __restrict__ seq_time,
    const int*   __restrict__ input_len,
    const float* __restrict__ emb,
    const float* __restrict__ bias_emb,
    const float* __restrict__ sel_W,
    const float* __restrict__ sel_b,
    const float* __restrict__ time_W,
    const float* __restrict__ time_b,
    float* __restrict__ out, u16* __restrict__ oh, u16* __restrict__ ol)
{
    const int tok = blockIdx.x;
    const int b   = tok >> 9;
    const int s   = tok & 511;
    const int d   = threadIdx.x;

    __shared__ float f[64];
    __shared__ int   codes[16];
    __shared__ float mcode[16];

    if (d < 64) {
        float t = seq_time[tok] * (1.0f / 7200.0f);
        float h = t * sel_W[d] + sel_b[d];
        f[d] = 1.0f - tanhf(h * h);
    }
    if (d >= 64 && d < 80) {
        int c = d - 64;
        codes[c] = event_code[tok * CC + c];
        mcode[c] = mask_code[tok * CC + c];
    }
    __syncthreads();

    float acc = bias_emb[d] + time_b[d];
    #pragma unroll
    for (int c = 0; c < CC; ++c)
        acc += emb[(long)codes[c] * DD + d] * mcode[c];
    #pragma unroll 8
    for (int j = 0; j < 64; ++j)
        acc += f[j] * time_W[j * DD + d];

    int pos = s + 1;
    if (pos <= input_len[b]) {
        int p = pos - 1;
        float e    = (float)(d & ~1) * (1.0f / 512.0f);
        float invf = exp2f(-13.287712379549449f * e);  // 10000^-e
        float ang  = (float)p * invf;
        acc += (d & 1) ? cosf(ang) : sinf(ang);
    }
    long o = (long)tok * DD + d;
    out[o] = acc;
    u16 hh = f2bf(acc);
    oh[o] = hh;
    ol[o] = f2bf(acc - bf2f(hh));
}

// ---------------------------------------------------------------------------
// Kernel 2: split-bf16 MFMA GEMM.  C[M,N] = (Ah+Al)[M,K] @ (Bh+Bl)^T[N,K]
// BM=128, BK=32, 256 threads = 4 waves in 2x2; per-wave 64 x (BN/2).
// 3 MFMA per frag pair: hi*hi + hi*lo + lo*hi (lo*lo ~2^-16, dropped).
// LDS layout k-contiguous -> frag ds_read_b128 is a contiguous 1KB/wave
// (conflict-free); staging via global_load_lds width 16 (linear dest).
// ---------------------------------------------------------------------------
template<int BN, bool RELU, bool RES, bool EMITBF>
__global__ __launch_bounds__(256) void mgemm(
    const u16* __restrict__ Ah, const u16* __restrict__ Al,
    const u16* __restrict__ Bh, const u16* __restrict__ Bl,
    const float* __restrict__ bias, const float* __restrict__ res,
    float* __restrict__ C, u16* __restrict__ Ch, u16* __restrict__ Cl,
    int N, int K)
{
    constexpr int WN = BN / 2;
    constexpr int NI = WN / 16;
    __shared__ __align__(16) u16 Ah_s[128 * 32];
    __shared__ __align__(16) u16 Al_s[128 * 32];
    __shared__ __align__(16) u16 Bh_s[BN * 32];
    __shared__ __align__(16) u16 Bl_s[BN * 32];

    const int tid  = threadIdx.x;
    const int wid  = tid >> 6, lane = tid & 63;
    const int wr   = wid >> 1, wc = wid & 1;
    const int l4   = lane >> 4, l15 = lane & 15;
    const int m0   = blockIdx.y * 128, n0 = blockIdx.x * BN;
    const int sr   = lane >> 2, sc = lane & 3;    // staging: 16 rows x 4 chunks

    f32x4 acc[4][NI];
    #pragma unroll
    for (int mi = 0; mi < 4; ++mi)
        #pragma unroll
        for (int ni = 0; ni < NI; ++ni)
            acc[mi][ni] = (f32x4){0.f, 0.f, 0.f, 0.f};

    for (int k0 = 0; k0 < K; k0 += 32) {
        #pragma unroll
        for (int i = 0; i < 2; ++i) {               // A rows wid*32 .. +32
            int rr = wid * 32 + i * 16;
            long go = (long)(m0 + rr + sr) * K + k0 + sc * 8;
            gload16(Ah + go, &Ah_s[rr * 32]);
            gload16(Al + go, &Al_s[rr * 32]);
        }
        #pragma unroll
        for (int i = 0; i < BN / 64; ++i) {         // B rows wid*(BN/4) ..
            int rr = wid * (BN / 4) + i * 16;
            long go = (long)(n0 + rr + sr) * K + k0 + sc * 8;
            gload16(Bh + go, &Bh_s[rr * 32]);
            gload16(Bl + go, &Bl_s[rr * 32]);
        }
        __syncthreads();   // drains vmcnt before use

        bf16x8 ah[4], al[4], bh[NI], bl[NI];
        #pragma unroll
        for (int mi = 0; mi < 4; ++mi) {
            int row = wr * 64 + mi * 16 + l15;
            ah[mi] = *(const bf16x8*)&Ah_s[row * 32 + l4 * 8];
            al[mi] = *(const bf16x8*)&Al_s[row * 32 + l4 * 8];
        }
        #pragma unroll
        for (int ni = 0; ni < NI; ++ni) {
            int row = wc * WN + ni * 16 + l15;
            bh[ni] = *(const bf16x8*)&Bh_s[row * 32 + l4 * 8];
            bl[ni] = *(const bf16x8*)&Bl_s[row * 32 + l4 * 8];
        }
        #pragma unroll
        for (int mi = 0; mi < 4; ++mi)
            #pragma unroll
            for (int ni = 0; ni < NI; ++ni) {
                acc[mi][ni] = __builtin_amdgcn_mfma_f32_16x16x32_bf16(ah[mi], bh[ni], acc[mi][ni], 0, 0, 0);
                acc[mi][ni] = __builtin_amdgcn_mfma_f32_16x16x32_bf16(ah[mi], bl[ni], acc[mi][ni], 0, 0, 0);
                acc[mi][ni] = __builtin_amdgcn_mfma_f32_16x16x32_bf16(al[mi], bh[ni], acc[mi][ni], 0, 0, 0);
            }
        __syncthreads();
    }

    // epilogue: C/D frag mapping col = lane&15, row = (lane>>4)*4 + reg
    #pragma unroll
    for (int mi = 0; mi < 4; ++mi)
        #pragma unroll
        for (int ni = 0; ni < NI; ++ni) {
            int col = n0 + wc * WN + ni * 16 + l15;
            float bv = bias[col];
            #pragma unroll
            for (int r = 0; r < 4; ++r) {
                int row = m0 + wr * 64 + mi * 16 + l4 * 4 + r;
                long off = (long)row * N + col;
                float v = acc[mi][ni][r] + bv;
                if (RES) v += res[off];
                if (RELU) v = fmaxf(v, 0.f);
                if (EMITBF) {
                    u16 hh = f2bf(v);
                    Ch[off] = hh;
                    Cl[off] = f2bf(v - bf2f(hh));
                } else {
                    C[off] = v;
                }
            }
        }
}

// ---------------------------------------------------------------------------
// Kernel 3: attention (contiguous-reinterpret groups, faithful no-mask).
// 4 threads/query, defer-threshold online softmax. Emits bf16 hi/lo ctx.
// ---------------------------------------------------------------------------
__global__ __launch_bounds__(256) void attn_kernel(
    const float* __restrict__ Q,
    const float* __restrict__ K,
    const float* __restrict__ V,
    u16* __restrict__ Oh, u16* __restrict__ Ol)
{
    const int g     = blockIdx.x >> 3;
    const int qt    = blockIdx.x & 7;
    const int tid   = threadIdx.x;
    const int qi    = tid >> 2;
    const int quart = tid & 3;
    const int r     = qt * 64 + qi;

    __shared__ float4 Ks[64][16];
    __shared__ float4 Vs[64][16];

    const float4* qp = (const float4*)(Q + (long)g * GRP + (long)r * DH) + quart * 4;
    float4 q0 = qp[0], q1 = qp[1], q2 = qp[2], q3 = qp[3];

    float4 a0 = {0,0,0,0}, a1 = {0,0,0,0}, a2 = {0,0,0,0}, a3 = {0,0,0,0};
    float m = -1e30f, l = 0.f;

    for (int kt = 0; kt < 8; ++kt) {
        __syncthreads();
        const float4* kb = (const float4*)(K + (long)g * GRP + (long)kt * 4096);
        const float4* vb = (const float4*)(V + (long)g * GRP + (long)kt * 4096);
        float4* ksl = (float4*)Ks;
        float4* vsl = (float4*)Vs;
        #pragma unroll
        for (int j = 0; j < 4; ++j) {
            ksl[tid + j * 256] = kb[tid + j * 256];
            vsl[tid + j * 256] = vb[tid + j * 256];
        }
        __syncthreads();

        #pragma unroll 4
        for (int kk = 0; kk < 64; ++kk) {
            float4 k0 = Ks[kk][quart * 4 + 0];
            float4 k1 = Ks[kk][quart * 4 + 1];
            float4 k2 = Ks[kk][quart * 4 + 2];
            float4 k3 = Ks[kk][quart * 4 + 3];
            float s0 = fmaf(q0.x, k0.x, fmaf(q0.y, k0.y, fmaf(q0.z, k0.z, q0.w * k0.w)));
            float s1 = fmaf(q1.x, k1.x, fmaf(q1.y, k1.y, fmaf(q1.z, k1.z, q1.w * k1.w)));
            float s2 = fmaf(q2.x, k2.x, fmaf(q2.y, k2.y, fmaf(q2.z, k2.z, q2.w * k2.w)));
            float s3 = fmaf(q3.x, k3.x, fmaf(q3.y, k3.y, fmaf(q3.z, k3.z, q3.w * k3.w)));
            float s = (s0 + s1) + (s2 + s3);
            s += __shfl_xor(s, 1);
            s += __shfl_xor(s, 2);
            s *= 0.125f;

            if (s - m > 8.0f) {
                float corr = __expf(m - s);
                l *= corr;
                a0.x *= corr; a0.y *= corr; a0.z *= corr; a0.w *= corr;
                a1.x *= corr; a1.y *= corr; a1.z *= corr; a1.w *= corr;
                a2.x *= corr; a2.y *= corr; a2.z *= corr; a2.w *= corr;
                a3.x *= corr; a3.y *= corr; a3.z *= corr; a3.w *= corr;
                m = s;
            }
            float p = __expf(s - m);
            l += p;
            float4 v0 = Vs[kk][quart * 4 + 0];
            float4 v1 = Vs[kk][quart * 4 + 1];
            float4 v2 = Vs[kk][quart * 4 + 2];
            float4 v3 = Vs[kk][quart * 4 + 3];
            a0.x = fmaf(p, v0.x, a0.x); a0.y = fmaf(p, v0.y, a0.y);
            a0.z = fmaf(p, v0.z, a0.z); a0.w = fmaf(p, v0.w, a0.w);
            a1.x = fmaf(p, v1.x, a1.x); a1.y = fmaf(p, v1.y, a1.y);
            a1.z = fmaf(p, v1.z, a1.z); a1.w = fmaf(p, v1.w, a1.w);
            a2.x = fmaf(p, v2.x, a2.x); a2.y = fmaf(p, v2.y, a2.y);
            a2.z = fmaf(p, v2.z, a2.z); a2.w = fmaf(p, v2.w, a2.w);
            a3.x = fmaf(p, v3.x, a3.x); a3.y = fmaf(p, v3.y, a3.y);
            a3.z = fmaf(p, v3.z, a3.z); a3.w = fmaf(p, v3.w, a3.w);
        }
    }

    float inv = 1.0f / l;
    float vals[16] = { a0.x, a0.y, a0.z, a0.w, a1.x, a1.y, a1.z, a1.w,
                       a2.x, a2.y, a2.z, a2.w, a3.x, a3.y, a3.z, a3.w };
    long base = (long)g * GRP + (long)r * DH + quart * 16;
    #pragma unroll
    for (int j = 0; j < 16; ++j) {
        float val = vals[j] * inv;
        u16 hh = f2bf(val);
        Oh[base + j] = hh;
        Ol[base + j] = f2bf(val - bf2f(hh));
    }
}

// ---------------------------------------------------------------------------
// Kernel 4: LayerNorm over D=512; emits fp32 + bf16 hi/lo
// ---------------------------------------------------------------------------
__global__ __launch_bounds__(256) void ln_kernel(
    const float* __restrict__ X,
    const float* __restrict__ gam,
    const float* __restrict__ bet,
    float* __restrict__ Y, u16* __restrict__ Yh, u16* __restrict__ Yl,
    float eps)
{
    const int row = blockIdx.x;
    const int tid = threadIdx.x;
    const float* x = X + (long)row * DD;

    float x0 = x[tid], x1 = x[tid + 256];
    __shared__ float ws4[4];
    const int wid = tid >> 6, lane = tid & 63;

    float sum = x0 + x1;
    #pragma unroll
    for (int off = 32; off > 0; off >>= 1) sum += __shfl_down(sum, off, 64);
    if (lane == 0) ws4[wid] = sum;
    __syncthreads();
    float mean = (ws4[0] + ws4[1] + ws4[2] + ws4[3]) * (1.0f / 512.0f);
    __syncthreads();

    float d0 = x0 - mean, d1 = x1 - mean;
    float s2 = d0 * d0 + d1 * d1;
    #pragma unroll
    for (int off = 32; off > 0; off >>= 1) s2 += __shfl_down(s2, off, 64);
    if (lane == 0) ws4[wid] = s2;
    __syncthreads();
    float var = (ws4[0] + ws4[1] + ws4[2] + ws4[3]) * (1.0f / 512.0f);
    float inv = rsqrtf(var + eps);

    float o0 = d0 * inv * gam[tid]       + bet[tid];
    float o1 = d1 * inv * gam[tid + 256] + bet[tid + 256];
    long b0 = (long)row * DD + tid;
    Y[b0] = o0;  Y[b0 + 256] = o1;
    u16 h0 = f2bf(o0), h1 = f2bf(o1);
    Yh[b0] = h0;       Yh[b0 + 256] = h1;
    Yl[b0] = f2bf(o0 - bf2f(h0));
    Yl[b0 + 256] = f2bf(o1 - bf2f(h1));
}

// ---------------------------------------------------------------------------
extern "C" void kernel_launch(void* const* d_in, const int* in_sizes, int n_in,
                              void* d_out, int out_size, void* d_ws, size_t ws_size,
                              hipStream_t stream)
{
    const int*   event_code = (const int*)  d_in[0];
    const float* mask_code  = (const float*)d_in[2];
    const float* seq_time   = (const float*)d_in[3];
    const int*   input_len  = (const int*)  d_in[6];
    const float* emb        = (const float*)d_in[7];
    const float* bias_emb   = (const float*)d_in[8];
    const float* sel_W      = (const float*)d_in[9];
    const float* sel_b      = (const float*)d_in[10];
    const float* time_W     = (const float*)d_in[11];
    const float* time_b     = (const float*)d_in[12];
    const float* Wq  = (const float*)d_in[13];
    const float* bq  = (const float*)d_in[14];
    const float* Wk  = (const float*)d_in[15];
    const float* bk  = (const float*)d_in[16];
    const float* Wv  = (const float*)d_in[17];
    const float* bv  = (const float*)d_in[18];
    const float* Wo  = (const float*)d_in[19];
    const float* bo  = (const float*)d_in[20];
    const float* ln1g = (const float*)d_in[21];
    const float* ln1b = (const float*)d_in[22];
    const float* W1  = (const float*)d_in[23];
    const float* b1  = (const float*)d_in[24];
    const float* W2  = (const float*)d_in[25];
    const float* b2  = (const float*)d_in[26];
    const float* ln2g = (const float*)d_in[27];
    const float* ln2b = (const float*)d_in[28];

    float* ws = (float*)d_ws;
    const long ND = (long)NTOK * DD;      // 4.19M elems
    float* x = ws;
    float* y = ws + ND;
    float* q = ws + 2 * ND;
    float* k = ws + 3 * ND;
    float* v = ws + 4 * ND;
    u16* a_hi = (u16*)(ws + 5 * ND);      // shared 512-wide bf16 activation pair
    u16* a_lo = a_hi + ND;
    u16* h_hi = a_lo + ND;                // FFN hidden bf16 [NTOK,2048]
    u16* h_lo = h_hi + 4 * ND;
    u16* wq_h = h_lo + 4 * ND;            // transposed bf16 weights
    const long SZQ = (long)LL * DD * DD, SZF = (long)LL * DD * FF;
    u16* wq_l = wq_h + SZQ;
    u16* wk_h = wq_l + SZQ;  u16* wk_l = wk_h + SZQ;
    u16* wv_h = wk_l + SZQ;  u16* wv_l = wv_h + SZQ;
    u16* wo_h = wv_l + SZQ;  u16* wo_l = wo_h + SZQ;
    u16* w1_h = wo_l + SZQ;  u16* w1_l = w1_h + SZF;
    u16* w2_h = w1_l + SZF;  u16* w2_l = w2_h + SZF;

    // weight transpose + split (runs every call; idempotent)
    cvt_weight<<<dim3(DD/32, DD/32, LL), 256, 0, stream>>>(Wq, wq_h, wq_l, DD, DD);
    cvt_weight<<<dim3(DD/32, DD/32, LL), 256, 0, stream>>>(Wk, wk_h, wk_l, DD, DD);
    cvt_weight<<<dim3(DD/32, DD/32, LL), 256, 0, stream>>>(Wv, wv_h, wv_l, DD, DD);
    cvt_weight<<<dim3(DD/32, DD/32, LL), 256, 0, stream>>>(Wo, wo_h, wo_l, DD, DD);
    cvt_weight<<<dim3(FF/32, DD/32, LL), 256, 0, stream>>>(W1, w1_h, w1_l, DD, FF);
    cvt_weight<<<dim3(DD/32, FF/32, LL), 256, 0, stream>>>(W2, w2_h, w2_l, FF, DD);

    embed_kernel<<<NTOK, 512, 0, stream>>>(event_code, mask_code, seq_time, input_len,
                                           emb, bias_emb, sel_W, sel_b, time_W, time_b,
                                           x, a_hi, a_lo);

    const dim3 gN512(DD / 64, NTOK / 128);   // (8,64)  = 512 blocks
    const dim3 gN2048(FF / 128, NTOK / 128); // (16,64) = 1024 blocks

    for (int l = 0; l < LL; ++l) {
        const u16* qh = wq_h + (long)l * DD * DD;  const u16* ql = wq_l + (long)l * DD * DD;
        const u16* kh = wk_h + (long)l * DD * DD;  const u16* kl = wk_l + (long)l * DD * DD;
        const u16* vh = wv_h + (long)l * DD * DD;  const u16* vl = wv_l + (long)l * DD * DD;
        const u16* oh = wo_h + (long)l * DD * DD;  const u16* ol = wo_l + (long)l * DD * DD;
        const u16* f1h = w1_h + (long)l * DD * FF; const u16* f1l = w1_l + (long)l * DD * FF;
        const u16* f2h = w2_h + (long)l * FF * DD; const u16* f2l = w2_l + (long)l * FF * DD;

        mgemm<64,false,false,false><<<gN512, 256, 0, stream>>>(a_hi, a_lo, qh, ql, bq + l*DD, nullptr, q, nullptr, nullptr, DD, DD);
        mgemm<64,false,false,false><<<gN512, 256, 0, stream>>>(a_hi, a_lo, kh, kl, bk + l*DD, nullptr, k, nullptr, nullptr, DD, DD);
        mgemm<64,false,false,false><<<gN512, 256, 0, stream>>>(a_hi, a_lo, vh, vl, bv + l*DD, nullptr, v, nullptr, nullptr, DD, DD);

        // ctx (bf16 hi/lo) overwrites a_hi/a_lo (QKV already consumed them)
        attn_kernel<<<NG * 8, 256, 0, stream>>>(q, k, v, a_hi, a_lo);

        // y = x + ctx@Wo + bo ; LN1 (eps 1e-3) emits y + y_hi/lo into a_*
        mgemm<64,false,true,false><<<gN512, 256, 0, stream>>>(a_hi, a_lo, oh, ol, bo + l*DD, x, y, nullptr, nullptr, DD, DD);
        ln_kernel<<<NTOK, 256, 0, stream>>>(y, ln1g + l*DD, ln1b + l*DD, y, a_hi, a_lo, 1e-3f);

        // h = relu(y@W1 + b1) emitted directly as bf16 hi/lo
        mgemm<128,true,false,true><<<gN2048, 256, 0, stream>>>(a_hi, a_lo, f1h, f1l, b1 + l*FF, nullptr, nullptr, h_hi, h_lo, FF, DD);
        // x = y + h@W2 + b2 ; LN2 (eps 1e-6) emits next-layer input
        mgemm<64,false,true,false><<<gN512, 256, 0, stream>>>(h_hi, h_lo, f2h, f2l, b2 + l*DD, y, x, nullptr, nullptr, DD, FF);

        float* lnout = (l == LL - 1) ? (float*)d_out : x;
        ln_kernel<<<NTOK, 256, 0, stream>>>(x, ln2g + l*DD, ln2b + l*DD, lnout, a_hi, a_lo, 1e-6f);
    }
}

// Round 4
// 828.739 us; speedup vs baseline: 2.8770x; 1.7604x over previous
//
#include <hip/hip_runtime.h>
#include <math.h>

// Problem constants
#define BB   16
#define SS   512
#define CC   16
#define DD   512
#define DH   64
#define FF   2048
#define LL   2
#define NTOK (BB*SS)      // 8192
#define NG   (BB*8)       // 128 attention groups
#define GRP  (SS*DH)      // 32768 elems per attention group slab
#define ST   72           // padded LDS row stride (u16) for attn tiles

typedef unsigned short u16;
typedef __attribute__((ext_vector_type(8))) short bf16x8;
typedef __attribute__((ext_vector_type(4))) float f32x4;

__device__ __forceinline__ u16 f2bf(float x) {
    unsigned u = __float_as_uint(x);
    u = (u + 0x7fffu + ((u >> 16) & 1u)) >> 16;
    return (u16)u;
}
__device__ __forceinline__ float bf2f(u16 h) {
    return __uint_as_float(((unsigned)h) << 16);
}
__device__ __forceinline__ void gload16(const void* g, void* l) {
    __builtin_amdgcn_global_load_lds((const __attribute__((address_space(1))) void*)g,
                                     (__attribute__((address_space(3))) void*)l, 16, 0, 0);
}

// ---------------------------------------------------------------------------
// Kernel 0: weight transpose + fp32 -> bf16 hi/lo split.  W[K][N] -> Wt[N][K]
// ---------------------------------------------------------------------------
__global__ __launch_bounds__(256) void cvt_weight(
    const float* __restrict__ W, u16* __restrict__ Th, u16* __restrict__ Tl,
    int K, int N)
{
    const long moff = (long)blockIdx.z * K * N;
    W  += moff; Th += moff; Tl += moff;
    const int n0 = blockIdx.x * 32, k0 = blockIdx.y * 32;
    __shared__ float T[32][33];
    const int t = threadIdx.x;

    {
        const int lk = t >> 3, ln4 = (t & 7) * 4;
        float4 w4 = *(const float4*)&W[(long)(k0 + lk) * N + n0 + ln4];
        T[ln4 + 0][lk] = w4.x; T[ln4 + 1][lk] = w4.y;
        T[ln4 + 2][lk] = w4.z; T[ln4 + 3][lk] = w4.w;
    }
    __syncthreads();
    {
        const int nn = t >> 3, kq = (t & 7) * 4;
        float v0 = T[nn][kq + 0], v1 = T[nn][kq + 1];
        float v2 = T[nn][kq + 2], v3 = T[nn][kq + 3];
        ushort4 hh, ll;
        hh.x = f2bf(v0); ll.x = f2bf(v0 - bf2f(hh.x));
        hh.y = f2bf(v1); ll.y = f2bf(v1 - bf2f(hh.y));
        hh.z = f2bf(v2); ll.z = f2bf(v2 - bf2f(hh.z));
        hh.w = f2bf(v3); ll.w = f2bf(v3 - bf2f(hh.w));
        long o = (long)(n0 + nn) * K + k0 + kq;
        *(ushort4*)&Th[o] = hh;
        *(ushort4*)&Tl[o] = ll;
    }
}

// ---------------------------------------------------------------------------
// Kernel 1: embedding sum + time MLP + positional encoding; emits fp32 + hi/lo
// ---------------------------------------------------------------------------
__global__ __launch_bounds__(512) void embed_kernel(
    const int*   __restrict__ event_code,
    const float* __restrict__ mask_code,
    const float* __restrict__ seq_time,
    const int*   __restrict__ input_len,
    const float* __restrict__ emb,
    const float* __restrict__ bias_emb,
    const float* __restrict__ sel_W,
    const float* __restrict__ sel_b,
    const float* __restrict__ time_W,
    const float* __restrict__ time_b,
    float* __restrict__ out, u16* __restrict__ oh, u16* __restrict__ ol)
{
    const int tok = blockIdx.x;
    const int b   = tok >> 9;
    const int s   = tok & 511;
    const int d   = threadIdx.x;

    __shared__ float f[64];
    __shared__ int   codes[16];
    __shared__ float mcode[16];

    if (d < 64) {
        float t = seq_time[tok] * (1.0f / 7200.0f);
        float h = t * sel_W[d] + sel_b[d];
        f[d] = 1.0f - tanhf(h * h);
    }
    if (d >= 64 && d < 80) {
        int c = d - 64;
        codes[c] = event_code[tok * CC + c];
        mcode[c] = mask_code[tok * CC + c];
    }
    __syncthreads();

    float acc = bias_emb[d] + time_b[d];
    #pragma unroll
    for (int c = 0; c < CC; ++c)
        acc += emb[(long)codes[c] * DD + d] * mcode[c];
    #pragma unroll 8
    for (int j = 0; j < 64; ++j)
        acc += f[j] * time_W[j * DD + d];

    int pos = s + 1;
    if (pos <= input_len[b]) {
        int p = pos - 1;
        float e    = (float)(d & ~1) * (1.0f / 512.0f);
        float invf = exp2f(-13.287712379549449f * e);  // 10000^-e
        float ang  = (float)p * invf;
        acc += (d & 1) ? cosf(ang) : sinf(ang);
    }
    long o = (long)tok * DD + d;
    out[o] = acc;
    u16 hh = f2bf(acc);
    oh[o] = hh;
    ol[o] = f2bf(acc - bf2f(hh));
}

// ---------------------------------------------------------------------------
// Kernel 2: split-bf16 MFMA GEMM.  C = (Ah+Al)[M,K] @ (Bh+Bl)^T[N,K]
// EMIT: 0 = fp32, 1 = bf16 hi/lo pair, 2 = bf16 single
// ---------------------------------------------------------------------------
template<int BN, bool RELU, bool RES, int EMIT>
__global__ __launch_bounds__(256) void mgemm(
    const u16* __restrict__ Ah, const u16* __restrict__ Al,
    const u16* __restrict__ Bh, const u16* __restrict__ Bl,
    const float* __restrict__ bias, const float* __restrict__ res,
    float* __restrict__ C, u16* __restrict__ Ch, u16* __restrict__ Cl,
    int N, int K)
{
    constexpr int WN = BN / 2;
    constexpr int NI = WN / 16;
    __shared__ __align__(16) u16 Ah_s[128 * 32];
    __shared__ __align__(16) u16 Al_s[128 * 32];
    __shared__ __align__(16) u16 Bh_s[BN * 32];
    __shared__ __align__(16) u16 Bl_s[BN * 32];

    const int tid  = threadIdx.x;
    const int wid  = tid >> 6, lane = tid & 63;
    const int wr   = wid >> 1, wc = wid & 1;
    const int l4   = lane >> 4, l15 = lane & 15;
    const int m0   = blockIdx.y * 128, n0 = blockIdx.x * BN;
    const int sr   = lane >> 2, sc = lane & 3;

    f32x4 acc[4][NI];
    #pragma unroll
    for (int mi = 0; mi < 4; ++mi)
        #pragma unroll
        for (int ni = 0; ni < NI; ++ni)
            acc[mi][ni] = (f32x4){0.f, 0.f, 0.f, 0.f};

    for (int k0 = 0; k0 < K; k0 += 32) {
        #pragma unroll
        for (int i = 0; i < 2; ++i) {
            int rr = wid * 32 + i * 16;
            long go = (long)(m0 + rr + sr) * K + k0 + sc * 8;
            gload16(Ah + go, &Ah_s[rr * 32]);
            gload16(Al + go, &Al_s[rr * 32]);
        }
        #pragma unroll
        for (int i = 0; i < BN / 64; ++i) {
            int rr = wid * (BN / 4) + i * 16;
            long go = (long)(n0 + rr + sr) * K + k0 + sc * 8;
            gload16(Bh + go, &Bh_s[rr * 32]);
            gload16(Bl + go, &Bl_s[rr * 32]);
        }
        __syncthreads();

        bf16x8 ah[4], al[4], bh[NI], bl[NI];
        #pragma unroll
        for (int mi = 0; mi < 4; ++mi) {
            int row = wr * 64 + mi * 16 + l15;
            ah[mi] = *(const bf16x8*)&Ah_s[row * 32 + l4 * 8];
            al[mi] = *(const bf16x8*)&Al_s[row * 32 + l4 * 8];
        }
        #pragma unroll
        for (int ni = 0; ni < NI; ++ni) {
            int row = wc * WN + ni * 16 + l15;
            bh[ni] = *(const bf16x8*)&Bh_s[row * 32 + l4 * 8];
            bl[ni] = *(const bf16x8*)&Bl_s[row * 32 + l4 * 8];
        }
        #pragma unroll
        for (int mi = 0; mi < 4; ++mi)
            #pragma unroll
            for (int ni = 0; ni < NI; ++ni) {
                acc[mi][ni] = __builtin_amdgcn_mfma_f32_16x16x32_bf16(ah[mi], bh[ni], acc[mi][ni], 0, 0, 0);
                acc[mi][ni] = __builtin_amdgcn_mfma_f32_16x16x32_bf16(ah[mi], bl[ni], acc[mi][ni], 0, 0, 0);
                acc[mi][ni] = __builtin_amdgcn_mfma_f32_16x16x32_bf16(al[mi], bh[ni], acc[mi][ni], 0, 0, 0);
            }
        __syncthreads();
    }

    #pragma unroll
    for (int mi = 0; mi < 4; ++mi)
        #pragma unroll
        for (int ni = 0; ni < NI; ++ni) {
            int col = n0 + wc * WN + ni * 16 + l15;
            float bv = bias[col];
            #pragma unroll
            for (int r = 0; r < 4; ++r) {
                int row = m0 + wr * 64 + mi * 16 + l4 * 4 + r;
                long off = (long)row * N + col;
                float v = acc[mi][ni][r] + bv;
                if (RES) v += res[off];
                if (RELU) v = fmaxf(v, 0.f);
                if (EMIT == 1) {
                    u16 hh = f2bf(v);
                    Ch[off] = hh;
                    Cl[off] = f2bf(v - bf2f(hh));
                } else if (EMIT == 2) {
                    Ch[off] = f2bf(v);
                } else {
                    C[off] = v;
                }
            }
        }
}

// ---------------------------------------------------------------------------
// Kernel 3: MFMA flash-attention over 128 contiguous [512x64] slabs.
// Block = group g, 64-query tile qt; 4 waves x 16 queries.
// S^T = mfma(K,Q) -> per-query softmax lane-local (q = lane&15) ->
// P via LDS round-trip -> O += mfma(P, V^T). Faithful: no padding mask.
// ---------------------------------------------------------------------------
__global__ __launch_bounds__(256) void attn_kernel(
    const u16* __restrict__ Qg, const u16* __restrict__ Kg, const u16* __restrict__ Vg,
    u16* __restrict__ Oh, u16* __restrict__ Ol)
{
    const int g   = blockIdx.x >> 3;
    const int qt  = blockIdx.x & 7;
    const int tid = threadIdx.x;
    const int w   = tid >> 6;          // wave 0..3 -> queries w*16..+15
    const int lane = tid & 63;
    const int l4  = lane >> 4, l15 = lane & 15;

    __shared__ __align__(16) u16 Qs[64 * ST];
    __shared__ __align__(16) u16 Ks[64 * ST];
    __shared__ __align__(16) u16 Vt[64 * ST];   // V^T: [d][k]
    __shared__ __align__(16) u16 Ps[64 * ST];   // P:   [q][k]

    const long gbase = (long)g * GRP;

    // stage Q tile (64x64 bf16, rows qt*64..)
    {
        const u16* src = Qg + gbase + (long)qt * 64 * 64;
        #pragma unroll
        for (int i = 0; i < 2; ++i) {
            int slot = tid + i * 256;            // 512 slots of 8 u16
            int row = slot >> 3, c8 = slot & 7;
            *(int4*)&Qs[row * ST + c8 * 8] = *(const int4*)&src[row * 64 + c8 * 8];
        }
    }
    __syncthreads();

    const bf16x8 qf0 = *(const bf16x8*)&Qs[(w * 16 + l15) * ST + l4 * 8];
    const bf16x8 qf1 = *(const bf16x8*)&Qs[(w * 16 + l15) * ST + 32 + l4 * 8];

    f32x4 oacc[4];
    #pragma unroll
    for (int db = 0; db < 4; ++db) oacc[db] = (f32x4){0.f, 0.f, 0.f, 0.f};
    float mrun = -3e38f, lrun = 0.f;

    const int k0t = (tid >> 4) * 4;    // V-transpose: key rows k0t..k0t+3
    const int d0t = (tid & 15) * 4;    // dims d0t..d0t+3

    for (int kt = 0; kt < 8; ++kt) {
        const u16* ksrc = Kg + gbase + (long)kt * 4096;
        const u16* vsrc = Vg + gbase + (long)kt * 4096;
        #pragma unroll
        for (int i = 0; i < 2; ++i) {
            int slot = tid + i * 256;
            int row = slot >> 3, c8 = slot & 7;
            *(int4*)&Ks[row * ST + c8 * 8] = *(const int4*)&ksrc[row * 64 + c8 * 8];
        }
        {   // V 4x4 register transpose -> Vt[d][k]
            ushort4 r0 = *(const ushort4*)&vsrc[(k0t + 0) * 64 + d0t];
            ushort4 r1 = *(const ushort4*)&vsrc[(k0t + 1) * 64 + d0t];
            ushort4 r2 = *(const ushort4*)&vsrc[(k0t + 2) * 64 + d0t];
            ushort4 r3 = *(const ushort4*)&vsrc[(k0t + 3) * 64 + d0t];
            ushort4 t0, t1, t2, t3;
            t0.x = r0.x; t0.y = r1.x; t0.z = r2.x; t0.w = r3.x;
            t1.x = r0.y; t1.y = r1.y; t1.z = r2.y; t1.w = r3.y;
            t2.x = r0.z; t2.y = r1.z; t2.z = r2.z; t2.w = r3.z;
            t3.x = r0.w; t3.y = r1.w; t3.z = r2.w; t3.w = r3.w;
            *(ushort4*)&Vt[(d0t + 0) * ST + k0t] = t0;
            *(ushort4*)&Vt[(d0t + 1) * ST + k0t] = t1;
            *(ushort4*)&Vt[(d0t + 2) * ST + k0t] = t2;
            *(ushort4*)&Vt[(d0t + 3) * ST + k0t] = t3;
        }
        __syncthreads();

        // QK^T (swapped): sacc[kb] = S^T frag, rows=keys kb*16.., cols=queries
        f32x4 sacc[4];
        #pragma unroll
        for (int kb = 0; kb < 4; ++kb) {
            bf16x8 a0 = *(const bf16x8*)&Ks[(kb * 16 + l15) * ST + l4 * 8];
            bf16x8 a1 = *(const bf16x8*)&Ks[(kb * 16 + l15) * ST + 32 + l4 * 8];
            f32x4 z = (f32x4){0.f, 0.f, 0.f, 0.f};
            z = __builtin_amdgcn_mfma_f32_16x16x32_bf16(a0, qf0, z, 0, 0, 0);
            z = __builtin_amdgcn_mfma_f32_16x16x32_bf16(a1, qf1, z, 0, 0, 0);
            sacc[kb] = z;
        }

        // online softmax: this lane owns query q = w*16 + l15,
        // holding keys {kb*16 + l4*4 + r}
        float pm = -3e38f;
        #pragma unroll
        for (int kb = 0; kb < 4; ++kb)
            #pragma unroll
            for (int r = 0; r < 4; ++r)
                pm = fmaxf(pm, sacc[kb][r]);
        pm *= 0.125f;
        pm = fmaxf(pm, __shfl_xor(pm, 16));
        pm = fmaxf(pm, __shfl_xor(pm, 32));
        float mn   = fmaxf(mrun, pm);
        float corr = __expf(mrun - mn);     // first tile: exp(-huge) = 0
        float psum = 0.f;
        u16 pb[16];
        #pragma unroll
        for (int kb = 0; kb < 4; ++kb)
            #pragma unroll
            for (int r = 0; r < 4; ++r) {
                float p = __expf(sacc[kb][r] * 0.125f - mn);
                u16 b = f2bf(p);
                pb[kb * 4 + r] = b;
                psum += bf2f(b);            // sum the rounded values (consistency)
            }
        psum += __shfl_xor(psum, 16);
        psum += __shfl_xor(psum, 32);
        lrun = lrun * corr + psum;
        mrun = mn;

        // write P[q][k] (wave-local rows)
        #pragma unroll
        for (int kb = 0; kb < 4; ++kb)
            #pragma unroll
            for (int r = 0; r < 4; ++r)
                Ps[(w * 16 + l15) * ST + kb * 16 + l4 * 4 + r] = pb[kb * 4 + r];

        // rescale O accum: O-frag row index is l4*4+r, corr lives at lane q
        float cr[4];
        #pragma unroll
        for (int r = 0; r < 4; ++r) cr[r] = __shfl(corr, l4 * 4 + r);
        #pragma unroll
        for (int db = 0; db < 4; ++db)
            #pragma unroll
            for (int r = 0; r < 4; ++r)
                oacc[db][r] *= cr[r];

        // drain wave-local P writes, then PV
        asm volatile("s_waitcnt lgkmcnt(0)" ::: "memory");
        __builtin_amdgcn_sched_barrier(0);
        bf16x8 pa0 = *(const bf16x8*)&Ps[(w * 16 + l15) * ST + l4 * 8];
        bf16x8 pa1 = *(const bf16x8*)&Ps[(w * 16 + l15) * ST + 32 + l4 * 8];
        #pragma unroll
        for (int db = 0; db < 4; ++db) {
            bf16x8 v0 = *(const bf16x8*)&Vt[(db * 16 + l15) * ST + l4 * 8];
            bf16x8 v1 = *(const bf16x8*)&Vt[(db * 16 + l15) * ST + 32 + l4 * 8];
            oacc[db] = __builtin_amdgcn_mfma_f32_16x16x32_bf16(pa0, v0, oacc[db], 0, 0, 0);
            oacc[db] = __builtin_amdgcn_mfma_f32_16x16x32_bf16(pa1, v1, oacc[db], 0, 0, 0);
        }
        __syncthreads();
    }

    // epilogue: O[q][d] / l_q, emit bf16 hi/lo ctx
    float li[4];
    #pragma unroll
    for (int r = 0; r < 4; ++r) li[r] = 1.0f / __shfl(lrun, l4 * 4 + r);
    #pragma unroll
    for (int db = 0; db < 4; ++db)
        #pragma unroll
        for (int r = 0; r < 4; ++r) {
            float val = oacc[db][r] * li[r];
            long addr = gbase + (long)(qt * 64 + w * 16 + l4 * 4 + r) * 64 + db * 16 + l15;
            u16 hh = f2bf(val);
            Oh[addr] = hh;
            Ol[addr] = f2bf(val - bf2f(hh));
        }
}

// ---------------------------------------------------------------------------
// Kernel 4: LayerNorm over D=512; emits fp32 + bf16 hi/lo
// ---------------------------------------------------------------------------
__global__ __launch_bounds__(256) void ln_kernel(
    const float* __restrict__ X,
    const float* __restrict__ gam,
    const float* __restrict__ bet,
    float* __restrict__ Y, u16* __restrict__ Yh, u16* __restrict__ Yl,
    float eps)
{
    const int row = blockIdx.x;
    const int tid = threadIdx.x;
    const float* x = X + (long)row * DD;

    float x0 = x[tid], x1 = x[tid + 256];
    __shared__ float ws4[4];
    const int wid = tid >> 6, lane = tid & 63;

    float sum = x0 + x1;
    #pragma unroll
    for (int off = 32; off > 0; off >>= 1) sum += __shfl_down(sum, off, 64);
    if (lane == 0) ws4[wid] = sum;
    __syncthreads();
    float mean = (ws4[0] + ws4[1] + ws4[2] + ws4[3]) * (1.0f / 512.0f);
    __syncthreads();

    float d0 = x0 - mean, d1 = x1 - mean;
    float s2 = d0 * d0 + d1 * d1;
    #pragma unroll
    for (int off = 32; off > 0; off >>= 1) s2 += __shfl_down(s2, off, 64);
    if (lane == 0) ws4[wid] = s2;
    __syncthreads();
    float var = (ws4[0] + ws4[1] + ws4[2] + ws4[3]) * (1.0f / 512.0f);
    float inv = rsqrtf(var + eps);

    float o0 = d0 * inv * gam[tid]       + bet[tid];
    float o1 = d1 * inv * gam[tid + 256] + bet[tid + 256];
    long b0 = (long)row * DD + tid;
    Y[b0] = o0;  Y[b0 + 256] = o1;
    u16 h0 = f2bf(o0), h1 = f2bf(o1);
    Yh[b0] = h0;       Yh[b0 + 256] = h1;
    Yl[b0] = f2bf(o0 - bf2f(h0));
    Yl[b0 + 256] = f2bf(o1 - bf2f(h1));
}

// ---------------------------------------------------------------------------
extern "C" void kernel_launch(void* const* d_in, const int* in_sizes, int n_in,
                              void* d_out, int out_size, void* d_ws, size_t ws_size,
                              hipStream_t stream)
{
    const int*   event_code = (const int*)  d_in[0];
    const float* mask_code  = (const float*)d_in[2];
    const float* seq_time   = (const float*)d_in[3];
    const int*   input_len  = (const int*)  d_in[6];
    const float* emb        = (const float*)d_in[7];
    const float* bias_emb   = (const float*)d_in[8];
    const float* sel_W      = (const float*)d_in[9];
    const float* sel_b      = (const float*)d_in[10];
    const float* time_W     = (const float*)d_in[11];
    const float* time_b     = (const float*)d_in[12];
    const float* Wq  = (const float*)d_in[13];
    const float* bq  = (const float*)d_in[14];
    const float* Wk  = (const float*)d_in[15];
    const float* bk  = (const float*)d_in[16];
    const float* Wv  = (const float*)d_in[17];
    const float* bv  = (const float*)d_in[18];
    const float* Wo  = (const float*)d_in[19];
    const float* bo  = (const float*)d_in[20];
    const float* ln1g = (const float*)d_in[21];
    const float* ln1b = (const float*)d_in[22];
    const float* W1  = (const float*)d_in[23];
    const float* b1  = (const float*)d_in[24];
    const float* W2  = (const float*)d_in[25];
    const float* b2  = (const float*)d_in[26];
    const float* ln2g = (const float*)d_in[27];
    const float* ln2b = (const float*)d_in[28];

    float* ws = (float*)d_ws;
    const long ND = (long)NTOK * DD;      // 4.19M elems
    const long NF = (long)NTOK * FF;
    float* x = ws;
    float* y = ws + ND;
    u16* q16  = (u16*)(ws + 2 * ND);      // bf16 QKV
    u16* k16  = q16 + ND;
    u16* v16  = k16 + ND;
    u16* a_hi = v16 + ND;                 // 512-wide bf16 activation pair
    u16* a_lo = a_hi + ND;
    u16* h_hi = a_lo + ND;                // FFN hidden bf16 pair
    u16* h_lo = h_hi + NF;
    u16* wq_h = h_lo + NF;                // transposed bf16 weights
    const long SZQ = (long)LL * DD * DD, SZF = (long)LL * DD * FF;
    u16* wq_l = wq_h + SZQ;
    u16* wk_h = wq_l + SZQ;  u16* wk_l = wk_h + SZQ;
    u16* wv_h = wk_l + SZQ;  u16* wv_l = wv_h + SZQ;
    u16* wo_h = wv_l + SZQ;  u16* wo_l = wo_h + SZQ;
    u16* w1_h = wo_l + SZQ;  u16* w1_l = w1_h + SZF;
    u16* w2_h = w1_l + SZF;  u16* w2_l = w2_h + SZF;

    cvt_weight<<<dim3(DD/32, DD/32, LL), 256, 0, stream>>>(Wq, wq_h, wq_l, DD, DD);
    cvt_weight<<<dim3(DD/32, DD/32, LL), 256, 0, stream>>>(Wk, wk_h, wk_l, DD, DD);
    cvt_weight<<<dim3(DD/32, DD/32, LL), 256, 0, stream>>>(Wv, wv_h, wv_l, DD, DD);
    cvt_weight<<<dim3(DD/32, DD/32, LL), 256, 0, stream>>>(Wo, wo_h, wo_l, DD, DD);
    cvt_weight<<<dim3(FF/32, DD/32, LL), 256, 0, stream>>>(W1, w1_h, w1_l, DD, FF);
    cvt_weight<<<dim3(DD/32, FF/32, LL), 256, 0, stream>>>(W2, w2_h, w2_l, FF, DD);

    embed_kernel<<<NTOK, 512, 0, stream>>>(event_code, mask_code, seq_time, input_len,
                                           emb, bias_emb, sel_W, sel_b, time_W, time_b,
                                           x, a_hi, a_lo);

    const dim3 gN512(DD / 64, NTOK / 128);   // (8,64)  = 512 blocks
    const dim3 gN2048(FF / 128, NTOK / 128); // (16,64) = 1024 blocks

    for (int l = 0; l < LL; ++l) {
        const u16* qh = wq_h + (long)l * DD * DD;  const u16* ql = wq_l + (long)l * DD * DD;
        const u16* kh = wk_h + (long)l * DD * DD;  const u16* kl = wk_l + (long)l * DD * DD;
        const u16* vh = wv_h + (long)l * DD * DD;  const u16* vl = wv_l + (long)l * DD * DD;
        const u16* oh = wo_h + (long)l * DD * DD;  const u16* ol = wo_l + (long)l * DD * DD;
        const u16* f1h = w1_h + (long)l * DD * FF; const u16* f1l = w1_l + (long)l * DD * FF;
        const u16* f2h = w2_h + (long)l * FF * DD; const u16* f2l = w2_l + (long)l * FF * DD;

        // QKV projections -> bf16 directly
        mgemm<64,false,false,2><<<gN512, 256, 0, stream>>>(a_hi, a_lo, qh, ql, bq + l*DD, nullptr, nullptr, q16, nullptr, DD, DD);
        mgemm<64,false,false,2><<<gN512, 256, 0, stream>>>(a_hi, a_lo, kh, kl, bk + l*DD, nullptr, nullptr, k16, nullptr, DD, DD);
        mgemm<64,false,false,2><<<gN512, 256, 0, stream>>>(a_hi, a_lo, vh, vl, bv + l*DD, nullptr, nullptr, v16, nullptr, DD, DD);

        // ctx (bf16 hi/lo) into a_hi/a_lo
        attn_kernel<<<NG * 8, 256, 0, stream>>>(q16, k16, v16, a_hi, a_lo);

        // y = x + ctx@Wo + bo ; LN1 (eps 1e-3)
        mgemm<64,false,true,0><<<gN512, 256, 0, stream>>>(a_hi, a_lo, oh, ol, bo + l*DD, x, y, nullptr, nullptr, DD, DD);
        ln_kernel<<<NTOK, 256, 0, stream>>>(y, ln1g + l*DD, ln1b + l*DD, y, a_hi, a_lo, 1e-3f);

        // h = relu(y@W1 + b1) as bf16 hi/lo
        mgemm<128,true,false,1><<<gN2048, 256, 0, stream>>>(a_hi, a_lo, f1h, f1l, b1 + l*FF, nullptr, nullptr, h_hi, h_lo, FF, DD);
        // x = y + h@W2 + b2 ; LN2 (eps 1e-6)
        mgemm<64,false,true,0><<<gN512, 256, 0, stream>>>(h_hi, h_lo, f2h, f2l, b2 + l*DD, y, x, nullptr, nullptr, DD, FF);

        float* lnout = (l == LL - 1) ? (float*)d_out : x;
        ln_kernel<<<NTOK, 256, 0, stream>>>(x, ln2g + l*DD, ln2b + l*DD, lnout, a_hi, a_lo, 1e-6f);
    }
}

// Round 5
// 617.024 us; speedup vs baseline: 3.8642x; 1.3431x over previous
//
#include <hip/hip_runtime.h>
#include <math.h>

// Problem constants
#define BB   16
#define SS   512
#define CC   16
#define DD   512
#define DH   64
#define FF   2048
#define LL   2
#define NTOK (BB*SS)      // 8192
#define NG   (BB*8)       // 128 attention groups
#define GRP  (SS*DH)      // 32768 elems per attention group slab
#define ST   72           // padded LDS row stride (u16) for attn tiles

typedef unsigned short u16;
typedef __attribute__((ext_vector_type(8))) short bf16x8;
typedef __attribute__((ext_vector_type(4))) float f32x4;

__device__ __forceinline__ u16 f2bf(float x) {
    unsigned u = __float_as_uint(x);
    u = (u + 0x7fffu + ((u >> 16) & 1u)) >> 16;
    return (u16)u;
}
__device__ __forceinline__ float bf2f(u16 h) {
    return __uint_as_float(((unsigned)h) << 16);
}
__device__ __forceinline__ void gload16(const void* g, void* l) {
    __builtin_amdgcn_global_load_lds((const __attribute__((address_space(1))) void*)g,
                                     (__attribute__((address_space(3))) void*)l, 16, 0, 0);
}

// ---------------------------------------------------------------------------
// Kernel 0: weight transpose + fp32 -> bf16 hi/lo split.  W[K][N] -> Wt[N][K]
// (weights keep hi/lo; activations are bf16-only)
// ---------------------------------------------------------------------------
__global__ __launch_bounds__(256) void cvt_weight(
    const float* __restrict__ W, u16* __restrict__ Th, u16* __restrict__ Tl,
    int K, int N)
{
    const long moff = (long)blockIdx.z * K * N;
    W  += moff; Th += moff; Tl += moff;
    const int n0 = blockIdx.x * 32, k0 = blockIdx.y * 32;
    __shared__ float T[32][33];
    const int t = threadIdx.x;

    {
        const int lk = t >> 3, ln4 = (t & 7) * 4;
        float4 w4 = *(const float4*)&W[(long)(k0 + lk) * N + n0 + ln4];
        T[ln4 + 0][lk] = w4.x; T[ln4 + 1][lk] = w4.y;
        T[ln4 + 2][lk] = w4.z; T[ln4 + 3][lk] = w4.w;
    }
    __syncthreads();
    {
        const int nn = t >> 3, kq = (t & 7) * 4;
        float v0 = T[nn][kq + 0], v1 = T[nn][kq + 1];
        float v2 = T[nn][kq + 2], v3 = T[nn][kq + 3];
        ushort4 hh, ll;
        hh.x = f2bf(v0); ll.x = f2bf(v0 - bf2f(hh.x));
        hh.y = f2bf(v1); ll.y = f2bf(v1 - bf2f(hh.y));
        hh.z = f2bf(v2); ll.z = f2bf(v2 - bf2f(hh.z));
        hh.w = f2bf(v3); ll.w = f2bf(v3 - bf2f(hh.w));
        long o = (long)(n0 + nn) * K + k0 + kq;
        *(ushort4*)&Th[o] = hh;
        *(ushort4*)&Tl[o] = ll;
    }
}

// ---------------------------------------------------------------------------
// Kernel 1: embedding sum + time MLP + positional encoding; fp32 + bf16 out
// ---------------------------------------------------------------------------
__global__ __launch_bounds__(512) void embed_kernel(
    const int*   __restrict__ event_code,
    const float* __restrict__ mask_code,
    const float* __restrict__ seq_time,
    const int*   __restrict__ input_len,
    const float* __restrict__ emb,
    const float* __restrict__ bias_emb,
    const float* __restrict__ sel_W,
    const float* __restrict__ sel_b,
    const float* __restrict__ time_W,
    const float* __restrict__ time_b,
    float* __restrict__ out, u16* __restrict__ oh)
{
    const int tok = blockIdx.x;
    const int b   = tok >> 9;
    const int s   = tok & 511;
    const int d   = threadIdx.x;

    __shared__ float f[64];
    __shared__ int   codes[16];
    __shared__ float mcode[16];

    if (d < 64) {
        float t = seq_time[tok] * (1.0f / 7200.0f);
        float h = t * sel_W[d] + sel_b[d];
        f[d] = 1.0f - tanhf(h * h);
    }
    if (d >= 64 && d < 80) {
        int c = d - 64;
        codes[c] = event_code[tok * CC + c];
        mcode[c] = mask_code[tok * CC + c];
    }
    __syncthreads();

    float acc = bias_emb[d] + time_b[d];
    #pragma unroll
    for (int c = 0; c < CC; ++c)
        acc += emb[(long)codes[c] * DD + d] * mcode[c];
    #pragma unroll 8
    for (int j = 0; j < 64; ++j)
        acc += f[j] * time_W[j * DD + d];

    int pos = s + 1;
    if (pos <= input_len[b]) {
        int p = pos - 1;
        float e    = (float)(d & ~1) * (1.0f / 512.0f);
        float invf = exp2f(-13.287712379549449f * e);  // 10000^-e
        float ang  = (float)p * invf;
        acc += (d & 1) ? cosf(ang) : sinf(ang);
    }
    long o = (long)tok * DD + d;
    out[o] = acc;
    oh[o] = f2bf(acc);
}

// ---------------------------------------------------------------------------
// Kernel 2: MFMA GEMM.  C = A_bf16[M,K] @ (Bh+Bl)^T[N,K]  (2 MFMA per pair)
// BM=128, BK=32, 4 waves 2x2. XCD-aware swizzle: all n-blocks of an M-panel
// on one XCD (A-panel fetched once per XCD). EMIT: 0 = fp32, 2 = bf16.
// ---------------------------------------------------------------------------
template<int BN, bool RELU, bool RES, int EMIT>
__global__ __launch_bounds__(256) void mgemm(
    const u16* __restrict__ A,
    const u16* __restrict__ Bh, const u16* __restrict__ Bl,
    const float* __restrict__ bias, const float* __restrict__ res,
    float* __restrict__ C, u16* __restrict__ Cb,
    int N, int K)
{
    constexpr int WN = BN / 2;
    constexpr int NI = WN / 16;
    __shared__ __align__(16) u16 A_s[128 * 32];
    __shared__ __align__(16) u16 Bh_s[BN * 32];
    __shared__ __align__(16) u16 Bl_s[BN * 32];

    const int tid  = threadIdx.x;
    const int wid  = tid >> 6, lane = tid & 63;
    const int wr   = wid >> 1, wc = wid & 1;
    const int l4   = lane >> 4, l15 = lane & 15;

    // XCD swizzle: panels [xcd*ppx, (xcd+1)*ppx) on XCD xcd (wg->XCD = bid%8)
    const int bid  = blockIdx.x + gridDim.x * blockIdx.y;
    const int xcd  = bid & 7;
    const int slot = bid >> 3;
    const int ppx  = gridDim.y >> 3;
    const int by   = xcd * ppx + slot / gridDim.x;
    const int bx   = slot % gridDim.x;
    const int m0   = by * 128, n0 = bx * BN;
    const int sr   = lane >> 2, sc = lane & 3;

    f32x4 acc[4][NI];
    #pragma unroll
    for (int mi = 0; mi < 4; ++mi)
        #pragma unroll
        for (int ni = 0; ni < NI; ++ni)
            acc[mi][ni] = (f32x4){0.f, 0.f, 0.f, 0.f};

    for (int k0 = 0; k0 < K; k0 += 32) {
        #pragma unroll
        for (int i = 0; i < 2; ++i) {
            int rr = wid * 32 + i * 16;
            long go = (long)(m0 + rr + sr) * K + k0 + sc * 8;
            gload16(A + go, &A_s[rr * 32]);
        }
        #pragma unroll
        for (int i = 0; i < BN / 64; ++i) {
            int rr = wid * (BN / 4) + i * 16;
            long go = (long)(n0 + rr + sr) * K + k0 + sc * 8;
            gload16(Bh + go, &Bh_s[rr * 32]);
            gload16(Bl + go, &Bl_s[rr * 32]);
        }
        __syncthreads();

        bf16x8 af[4], bh[NI], bl[NI];
        #pragma unroll
        for (int mi = 0; mi < 4; ++mi) {
            int row = wr * 64 + mi * 16 + l15;
            af[mi] = *(const bf16x8*)&A_s[row * 32 + l4 * 8];
        }
        #pragma unroll
        for (int ni = 0; ni < NI; ++ni) {
            int row = wc * WN + ni * 16 + l15;
            bh[ni] = *(const bf16x8*)&Bh_s[row * 32 + l4 * 8];
            bl[ni] = *(const bf16x8*)&Bl_s[row * 32 + l4 * 8];
        }
        #pragma unroll
        for (int mi = 0; mi < 4; ++mi)
            #pragma unroll
            for (int ni = 0; ni < NI; ++ni) {
                acc[mi][ni] = __builtin_amdgcn_mfma_f32_16x16x32_bf16(af[mi], bh[ni], acc[mi][ni], 0, 0, 0);
                acc[mi][ni] = __builtin_amdgcn_mfma_f32_16x16x32_bf16(af[mi], bl[ni], acc[mi][ni], 0, 0, 0);
            }
        __syncthreads();
    }

    #pragma unroll
    for (int mi = 0; mi < 4; ++mi)
        #pragma unroll
        for (int ni = 0; ni < NI; ++ni) {
            int col = n0 + wc * WN + ni * 16 + l15;
            float bv = bias[col];
            #pragma unroll
            for (int r = 0; r < 4; ++r) {
                int row = m0 + wr * 64 + mi * 16 + l4 * 4 + r;
                long off = (long)row * N + col;
                float v = acc[mi][ni][r] + bv;
                if (RES) v += res[off];
                if (RELU) v = fmaxf(v, 0.f);
                if (EMIT == 2) Cb[off] = f2bf(v);
                else           C[off]  = v;
            }
        }
}

// ---------------------------------------------------------------------------
// Kernel 3: MFMA flash-attention over 128 contiguous [512x64] slabs.
// XCD-swizzled so a group's 8 query-tile blocks share one XCD's L2 (K/V reuse).
// ---------------------------------------------------------------------------
__global__ __launch_bounds__(256) void attn_kernel(
    const u16* __restrict__ Qg, const u16* __restrict__ Kg, const u16* __restrict__ Vg,
    u16* __restrict__ Oh)
{
    const int bid = blockIdx.x;
    const int xcd = bid & 7, slot = bid >> 3;      // 1024 blocks
    const int g   = xcd * 16 + (slot >> 3);        // 16 groups per XCD
    const int qt  = slot & 7;
    const int tid = threadIdx.x;
    const int w   = tid >> 6;
    const int lane = tid & 63;
    const int l4  = lane >> 4, l15 = lane & 15;

    __shared__ __align__(16) u16 Qs[64 * ST];
    __shared__ __align__(16) u16 Ks[64 * ST];
    __shared__ __align__(16) u16 Vt[64 * ST];   // V^T: [d][k]
    __shared__ __align__(16) u16 Ps[64 * ST];   // P:   [q][k]

    const long gbase = (long)g * GRP;

    {
        const u16* src = Qg + gbase + (long)qt * 64 * 64;
        #pragma unroll
        for (int i = 0; i < 2; ++i) {
            int slot2 = tid + i * 256;
            int row = slot2 >> 3, c8 = slot2 & 7;
            *(int4*)&Qs[row * ST + c8 * 8] = *(const int4*)&src[row * 64 + c8 * 8];
        }
    }
    __syncthreads();

    const bf16x8 qf0 = *(const bf16x8*)&Qs[(w * 16 + l15) * ST + l4 * 8];
    const bf16x8 qf1 = *(const bf16x8*)&Qs[(w * 16 + l15) * ST + 32 + l4 * 8];

    f32x4 oacc[4];
    #pragma unroll
    for (int db = 0; db < 4; ++db) oacc[db] = (f32x4){0.f, 0.f, 0.f, 0.f};
    float mrun = -3e38f, lrun = 0.f;

    const int k0t = (tid >> 4) * 4;
    const int d0t = (tid & 15) * 4;

    for (int kt = 0; kt < 8; ++kt) {
        const u16* ksrc = Kg + gbase + (long)kt * 4096;
        const u16* vsrc = Vg + gbase + (long)kt * 4096;
        #pragma unroll
        for (int i = 0; i < 2; ++i) {
            int slot2 = tid + i * 256;
            int row = slot2 >> 3, c8 = slot2 & 7;
            *(int4*)&Ks[row * ST + c8 * 8] = *(const int4*)&ksrc[row * 64 + c8 * 8];
        }
        {   // V 4x4 register transpose -> Vt[d][k]
            ushort4 r0 = *(const ushort4*)&vsrc[(k0t + 0) * 64 + d0t];
            ushort4 r1 = *(const ushort4*)&vsrc[(k0t + 1) * 64 + d0t];
            ushort4 r2 = *(const ushort4*)&vsrc[(k0t + 2) * 64 + d0t];
            ushort4 r3 = *(const ushort4*)&vsrc[(k0t + 3) * 64 + d0t];
            ushort4 t0, t1, t2, t3;
            t0.x = r0.x; t0.y = r1.x; t0.z = r2.x; t0.w = r3.x;
            t1.x = r0.y; t1.y = r1.y; t1.z = r2.y; t1.w = r3.y;
            t2.x = r0.z; t2.y = r1.z; t2.z = r2.z; t2.w = r3.z;
            t3.x = r0.w; t3.y = r1.w; t3.z = r2.w; t3.w = r3.w;
            *(ushort4*)&Vt[(d0t + 0) * ST + k0t] = t0;
            *(ushort4*)&Vt[(d0t + 1) * ST + k0t] = t1;
            *(ushort4*)&Vt[(d0t + 2) * ST + k0t] = t2;
            *(ushort4*)&Vt[(d0t + 3) * ST + k0t] = t3;
        }
        __syncthreads();

        f32x4 sacc[4];
        #pragma unroll
        for (int kb = 0; kb < 4; ++kb) {
            bf16x8 a0 = *(const bf16x8*)&Ks[(kb * 16 + l15) * ST + l4 * 8];
            bf16x8 a1 = *(const bf16x8*)&Ks[(kb * 16 + l15) * ST + 32 + l4 * 8];
            f32x4 z = (f32x4){0.f, 0.f, 0.f, 0.f};
            z = __builtin_amdgcn_mfma_f32_16x16x32_bf16(a0, qf0, z, 0, 0, 0);
            z = __builtin_amdgcn_mfma_f32_16x16x32_bf16(a1, qf1, z, 0, 0, 0);
            sacc[kb] = z;
        }

        float pm = -3e38f;
        #pragma unroll
        for (int kb = 0; kb < 4; ++kb)
            #pragma unroll
            for (int r = 0; r < 4; ++r)
                pm = fmaxf(pm, sacc[kb][r]);
        pm *= 0.125f;
        pm = fmaxf(pm, __shfl_xor(pm, 16));
        pm = fmaxf(pm, __shfl_xor(pm, 32));
        float mn   = fmaxf(mrun, pm);
        float corr = __expf(mrun - mn);
        float psum = 0.f;
        u16 pb[16];
        #pragma unroll
        for (int kb = 0; kb < 4; ++kb)
            #pragma unroll
            for (int r = 0; r < 4; ++r) {
                float p = __expf(sacc[kb][r] * 0.125f - mn);
                u16 b = f2bf(p);
                pb[kb * 4 + r] = b;
                psum += bf2f(b);
            }
        psum += __shfl_xor(psum, 16);
        psum += __shfl_xor(psum, 32);
        lrun = lrun * corr + psum;
        mrun = mn;

        #pragma unroll
        for (int kb = 0; kb < 4; ++kb)
            #pragma unroll
            for (int r = 0; r < 4; ++r)
                Ps[(w * 16 + l15) * ST + kb * 16 + l4 * 4 + r] = pb[kb * 4 + r];

        float cr[4];
        #pragma unroll
        for (int r = 0; r < 4; ++r) cr[r] = __shfl(corr, l4 * 4 + r);
        #pragma unroll
        for (int db = 0; db < 4; ++db)
            #pragma unroll
            for (int r = 0; r < 4; ++r)
                oacc[db][r] *= cr[r];

        asm volatile("s_waitcnt lgkmcnt(0)" ::: "memory");
        __builtin_amdgcn_sched_barrier(0);
        bf16x8 pa0 = *(const bf16x8*)&Ps[(w * 16 + l15) * ST + l4 * 8];
        bf16x8 pa1 = *(const bf16x8*)&Ps[(w * 16 + l15) * ST + 32 + l4 * 8];
        #pragma unroll
        for (int db = 0; db < 4; ++db) {
            bf16x8 v0 = *(const bf16x8*)&Vt[(db * 16 + l15) * ST + l4 * 8];
            bf16x8 v1 = *(const bf16x8*)&Vt[(db * 16 + l15) * ST + 32 + l4 * 8];
            oacc[db] = __builtin_amdgcn_mfma_f32_16x16x32_bf16(pa0, v0, oacc[db], 0, 0, 0);
            oacc[db] = __builtin_amdgcn_mfma_f32_16x16x32_bf16(pa1, v1, oacc[db], 0, 0, 0);
        }
        __syncthreads();
    }

    float li[4];
    #pragma unroll
    for (int r = 0; r < 4; ++r) li[r] = 1.0f / __shfl(lrun, l4 * 4 + r);
    #pragma unroll
    for (int db = 0; db < 4; ++db)
        #pragma unroll
        for (int r = 0; r < 4; ++r) {
            float val = oacc[db][r] * li[r];
            long addr = gbase + (long)(qt * 64 + w * 16 + l4 * 4 + r) * 64 + db * 16 + l15;
            Oh[addr] = f2bf(val);
        }
}

// ---------------------------------------------------------------------------
// Kernel 4: LayerNorm over D=512; emits fp32 + bf16
// ---------------------------------------------------------------------------
__global__ __launch_bounds__(256) void ln_kernel(
    const float* __restrict__ X,
    const float* __restrict__ gam,
    const float* __restrict__ bet,
    float* __restrict__ Y, u16* __restrict__ Yh,
    float eps)
{
    const int row = blockIdx.x;
    const int tid = threadIdx.x;
    const float* x = X + (long)row * DD;

    float x0 = x[tid], x1 = x[tid + 256];
    __shared__ float ws4[4];
    const int wid = tid >> 6, lane = tid & 63;

    float sum = x0 + x1;
    #pragma unroll
    for (int off = 32; off > 0; off >>= 1) sum += __shfl_down(sum, off, 64);
    if (lane == 0) ws4[wid] = sum;
    __syncthreads();
    float mean = (ws4[0] + ws4[1] + ws4[2] + ws4[3]) * (1.0f / 512.0f);
    __syncthreads();

    float d0 = x0 - mean, d1 = x1 - mean;
    float s2 = d0 * d0 + d1 * d1;
    #pragma unroll
    for (int off = 32; off > 0; off >>= 1) s2 += __shfl_down(s2, off, 64);
    if (lane == 0) ws4[wid] = s2;
    __syncthreads();
    float var = (ws4[0] + ws4[1] + ws4[2] + ws4[3]) * (1.0f / 512.0f);
    float inv = rsqrtf(var + eps);

    float o0 = d0 * inv * gam[tid]       + bet[tid];
    float o1 = d1 * inv * gam[tid + 256] + bet[tid + 256];
    long b0 = (long)row * DD + tid;
    Y[b0] = o0;  Y[b0 + 256] = o1;
    Yh[b0] = f2bf(o0);
    Yh[b0 + 256] = f2bf(o1);
}

// ---------------------------------------------------------------------------
extern "C" void kernel_launch(void* const* d_in, const int* in_sizes, int n_in,
                              void* d_out, int out_size, void* d_ws, size_t ws_size,
                              hipStream_t stream)
{
    const int*   event_code = (const int*)  d_in[0];
    const float* mask_code  = (const float*)d_in[2];
    const float* seq_time   = (const float*)d_in[3];
    const int*   input_len  = (const int*)  d_in[6];
    const float* emb        = (const float*)d_in[7];
    const float* bias_emb   = (const float*)d_in[8];
    const float* sel_W      = (const float*)d_in[9];
    const float* sel_b      = (const float*)d_in[10];
    const float* time_W     = (const float*)d_in[11];
    const float* time_b     = (const float*)d_in[12];
    const float* Wq  = (const float*)d_in[13];
    const float* bq  = (const float*)d_in[14];
    const float* Wk  = (const float*)d_in[15];
    const float* bk  = (const float*)d_in[16];
    const float* Wv  = (const float*)d_in[17];
    const float* bv  = (const float*)d_in[18];
    const float* Wo  = (const float*)d_in[19];
    const float* bo  = (const float*)d_in[20];
    const float* ln1g = (const float*)d_in[21];
    const float* ln1b = (const float*)d_in[22];
    const float* W1  = (const float*)d_in[23];
    const float* b1  = (const float*)d_in[24];
    const float* W2  = (const float*)d_in[25];
    const float* b2  = (const float*)d_in[26];
    const float* ln2g = (const float*)d_in[27];
    const float* ln2b = (const float*)d_in[28];

    float* ws = (float*)d_ws;
    const long ND = (long)NTOK * DD;      // 4.19M elems
    const long NF = (long)NTOK * FF;
    float* x = ws;
    float* y = ws + ND;
    u16* q16 = (u16*)(ws + 2 * ND);       // bf16 QKV
    u16* k16 = q16 + ND;
    u16* v16 = k16 + ND;
    u16* a16 = v16 + ND;                  // bf16 activations (embed/LN/ctx)
    u16* h16 = a16 + ND;                  // FFN hidden bf16 [NTOK,FF]
    u16* wq_h = h16 + NF;                 // transposed bf16 hi/lo weights
    const long SZQ = (long)LL * DD * DD, SZF = (long)LL * DD * FF;
    u16* wq_l = wq_h + SZQ;
    u16* wk_h = wq_l + SZQ;  u16* wk_l = wk_h + SZQ;
    u16* wv_h = wk_l + SZQ;  u16* wv_l = wv_h + SZQ;
    u16* wo_h = wv_l + SZQ;  u16* wo_l = wo_h + SZQ;
    u16* w1_h = wo_l + SZQ;  u16* w1_l = w1_h + SZF;
    u16* w2_h = w1_l + SZF;  u16* w2_l = w2_h + SZF;

    cvt_weight<<<dim3(DD/32, DD/32, LL), 256, 0, stream>>>(Wq, wq_h, wq_l, DD, DD);
    cvt_weight<<<dim3(DD/32, DD/32, LL), 256, 0, stream>>>(Wk, wk_h, wk_l, DD, DD);
    cvt_weight<<<dim3(DD/32, DD/32, LL), 256, 0, stream>>>(Wv, wv_h, wv_l, DD, DD);
    cvt_weight<<<dim3(DD/32, DD/32, LL), 256, 0, stream>>>(Wo, wo_h, wo_l, DD, DD);
    cvt_weight<<<dim3(FF/32, DD/32, LL), 256, 0, stream>>>(W1, w1_h, w1_l, DD, FF);
    cvt_weight<<<dim3(DD/32, FF/32, LL), 256, 0, stream>>>(W2, w2_h, w2_l, FF, DD);

    embed_kernel<<<NTOK, 512, 0, stream>>>(event_code, mask_code, seq_time, input_len,
                                           emb, bias_emb, sel_W, sel_b, time_W, time_b,
                                           x, a16);

    const dim3 gN512(DD / 64, NTOK / 128);   // (8,64)  = 512 blocks
    const dim3 gN2048(FF / 128, NTOK / 128); // (16,64) = 1024 blocks

    for (int l = 0; l < LL; ++l) {
        const u16* qh = wq_h + (long)l * DD * DD;  const u16* ql = wq_l + (long)l * DD * DD;
        const u16* kh = wk_h + (long)l * DD * DD;  const u16* kl = wk_l + (long)l * DD * DD;
        const u16* vh = wv_h + (long)l * DD * DD;  const u16* vl = wv_l + (long)l * DD * DD;
        const u16* oh = wo_h + (long)l * DD * DD;  const u16* ol = wo_l + (long)l * DD * DD;
        const u16* f1h = w1_h + (long)l * DD * FF; const u16* f1l = w1_l + (long)l * DD * FF;
        const u16* f2h = w2_h + (long)l * FF * DD; const u16* f2l = w2_l + (long)l * FF * DD;

        // QKV projections -> bf16
        mgemm<64,false,false,2><<<gN512, 256, 0, stream>>>(a16, qh, ql, bq + l*DD, nullptr, nullptr, q16, DD, DD);
        mgemm<64,false,false,2><<<gN512, 256, 0, stream>>>(a16, kh, kl, bk + l*DD, nullptr, nullptr, k16, DD, DD);
        mgemm<64,false,false,2><<<gN512, 256, 0, stream>>>(a16, vh, vl, bv + l*DD, nullptr, nullptr, v16, DD, DD);

        // ctx (bf16) into a16
        attn_kernel<<<NG * 8, 256, 0, stream>>>(q16, k16, v16, a16);

        // y = x + ctx@Wo + bo ; LN1 (eps 1e-3)
        mgemm<64,false,true,0><<<gN512, 256, 0, stream>>>(a16, oh, ol, bo + l*DD, x, y, nullptr, DD, DD);
        ln_kernel<<<NTOK, 256, 0, stream>>>(y, ln1g + l*DD, ln1b + l*DD, y, a16, 1e-3f);

        // h = relu(y@W1 + b1) -> bf16
        mgemm<128,true,false,2><<<gN2048, 256, 0, stream>>>(a16, f1h, f1l, b1 + l*FF, nullptr, nullptr, h16, FF, DD);
        // x = y + h@W2 + b2 ; LN2 (eps 1e-6)
        mgemm<64,false,true,0><<<gN512, 256, 0, stream>>>(h16, f2h, f2l, b2 + l*DD, y, x, nullptr, DD, FF);

        float* lnout = (l == LL - 1) ? (float*)d_out : x;
        ln_kernel<<<NTOK, 256, 0, stream>>>(x, ln2g + l*DD, ln2b + l*DD, lnout, a16, 1e-6f);
    }
}

// Round 6
// 596.243 us; speedup vs baseline: 3.9989x; 1.0349x over previous
//
#include <hip/hip_runtime.h>
#include <math.h>

// Problem constants
#define BB   16
#define SS   512
#define CC   16
#define DD   512
#define DH   64
#define FF   2048
#define LL   2
#define VV   20000
#define NTOK (BB*SS)      // 8192
#define NG   (BB*8)       // 128 attention groups
#define GRP  (SS*DH)      // 32768 elems per attention group slab
#define ST   72           // padded LDS row stride (u16) for attn tiles

typedef unsigned short u16;
typedef __attribute__((ext_vector_type(8))) short bf16x8;
typedef __attribute__((ext_vector_type(4))) float f32x4;

__device__ __forceinline__ u16 f2bf(float x) {
    unsigned u = __float_as_uint(x);
    u = (u + 0x7fffu + ((u >> 16) & 1u)) >> 16;
    return (u16)u;
}
__device__ __forceinline__ float bf2f(u16 h) {
    return __uint_as_float(((unsigned)h) << 16);
}
__device__ __forceinline__ void gload16(const void* g, void* l) {
    __builtin_amdgcn_global_load_lds((const __attribute__((address_space(1))) void*)g,
                                     (__attribute__((address_space(3))) void*)l, 16, 0, 0);
}

// ---------------------------------------------------------------------------
// Kernel 0a: fused transpose+split for Wq/Wk/Wv/Wo.  QKV rows packed into one
// [L][1536][512] B-matrix (k-contiguous); Wo into [L][512][512].
// grid (16,16,8): z = which*2 + layer
// ---------------------------------------------------------------------------
__global__ __launch_bounds__(256) void cvt_qkvo(
    const float* __restrict__ Wq, const float* __restrict__ Wk,
    const float* __restrict__ Wv, const float* __restrict__ Wo,
    u16* __restrict__ qkv_h, u16* __restrict__ qkv_l,
    u16* __restrict__ o_h,   u16* __restrict__ o_l)
{
    const int z = blockIdx.z;
    const int which = z >> 1, l = z & 1;
    const float* W = (which == 0) ? Wq : (which == 1) ? Wk : (which == 2) ? Wv : Wo;
    W += (long)l * DD * DD;
    u16 *Th, *Tl;
    if (which < 3) {
        long off = (long)l * 1536 * DD + (long)which * DD * DD;
        Th = qkv_h + off; Tl = qkv_l + off;
    } else {
        long off = (long)l * DD * DD;
        Th = o_h + off;   Tl = o_l + off;
    }
    const int n0 = blockIdx.x * 32, k0 = blockIdx.y * 32;
    __shared__ float T[32][33];
    const int t = threadIdx.x;
    {
        const int lk = t >> 3, ln4 = (t & 7) * 4;
        float4 w4 = *(const float4*)&W[(long)(k0 + lk) * DD + n0 + ln4];
        T[ln4 + 0][lk] = w4.x; T[ln4 + 1][lk] = w4.y;
        T[ln4 + 2][lk] = w4.z; T[ln4 + 3][lk] = w4.w;
    }
    __syncthreads();
    {
        const int nn = t >> 3, kq = (t & 7) * 4;
        float v0 = T[nn][kq + 0], v1 = T[nn][kq + 1];
        float v2 = T[nn][kq + 2], v3 = T[nn][kq + 3];
        ushort4 hh, ll;
        hh.x = f2bf(v0); ll.x = f2bf(v0 - bf2f(hh.x));
        hh.y = f2bf(v1); ll.y = f2bf(v1 - bf2f(hh.y));
        hh.z = f2bf(v2); ll.z = f2bf(v2 - bf2f(hh.z));
        hh.w = f2bf(v3); ll.w = f2bf(v3 - bf2f(hh.w));
        long o = (long)(n0 + nn) * DD + k0 + kq;
        *(ushort4*)&Th[o] = hh;
        *(ushort4*)&Tl[o] = ll;
    }
}

// ---------------------------------------------------------------------------
// Kernel 0b: generic transpose+split (W1, W2). grid (N/32, K/32, L)
// ---------------------------------------------------------------------------
__global__ __launch_bounds__(256) void cvt_weight(
    const float* __restrict__ W, u16* __restrict__ Th, u16* __restrict__ Tl,
    int K, int N)
{
    const long moff = (long)blockIdx.z * K * N;
    W += moff; Th += moff; Tl += moff;
    const int n0 = blockIdx.x * 32, k0 = blockIdx.y * 32;
    __shared__ float T[32][33];
    const int t = threadIdx.x;
    {
        const int lk = t >> 3, ln4 = (t & 7) * 4;
        float4 w4 = *(const float4*)&W[(long)(k0 + lk) * N + n0 + ln4];
        T[ln4 + 0][lk] = w4.x; T[ln4 + 1][lk] = w4.y;
        T[ln4 + 2][lk] = w4.z; T[ln4 + 3][lk] = w4.w;
    }
    __syncthreads();
    {
        const int nn = t >> 3, kq = (t & 7) * 4;
        float v0 = T[nn][kq + 0], v1 = T[nn][kq + 1];
        float v2 = T[nn][kq + 2], v3 = T[nn][kq + 3];
        ushort4 hh, ll;
        hh.x = f2bf(v0); ll.x = f2bf(v0 - bf2f(hh.x));
        hh.y = f2bf(v1); ll.y = f2bf(v1 - bf2f(hh.y));
        hh.z = f2bf(v2); ll.z = f2bf(v2 - bf2f(hh.z));
        hh.w = f2bf(v3); ll.w = f2bf(v3 - bf2f(hh.w));
        long o = (long)(n0 + nn) * K + k0 + kq;
        *(ushort4*)&Th[o] = hh;
        *(ushort4*)&Tl[o] = ll;
    }
}

// ---------------------------------------------------------------------------
// Kernel 0c: embedding table fp32 -> bf16 (10.24M elems, 10000 blocks)
// ---------------------------------------------------------------------------
__global__ __launch_bounds__(256) void cvt_emb(const float* __restrict__ E,
                                               u16* __restrict__ E16)
{
    long i = ((long)blockIdx.x * 256 + threadIdx.x) * 4;
    float4 v = *(const float4*)&E[i];
    ushort4 o;
    o.x = f2bf(v.x); o.y = f2bf(v.y); o.z = f2bf(v.z); o.w = f2bf(v.w);
    *(ushort4*)&E16[i] = o;
}

// ---------------------------------------------------------------------------
// Kernel 1: embedding sum (bf16 gather) + time MLP + PE; 256 thr x 2 dims
// ---------------------------------------------------------------------------
__global__ __launch_bounds__(256) void embed_kernel(
    const int*   __restrict__ event_code,
    const float* __restrict__ mask_code,
    const float* __restrict__ seq_time,
    const int*   __restrict__ input_len,
    const u16*   __restrict__ emb16,
    const float* __restrict__ bias_emb,
    const float* __restrict__ sel_W,
    const float* __restrict__ sel_b,
    const float* __restrict__ time_W,
    const float* __restrict__ time_b,
    float* __restrict__ out, u16* __restrict__ oh)
{
    const int tok = blockIdx.x;
    const int b   = tok >> 9;
    const int s   = tok & 511;
    const int t2  = threadIdx.x;     // 0..255
    const int d   = t2 * 2;

    __shared__ float f[64];
    __shared__ int   codes[16];
    __shared__ float mcode[16];

    if (t2 < 64) {
        float t = seq_time[tok] * (1.0f / 7200.0f);
        float h = t * sel_W[t2] + sel_b[t2];
        f[t2] = 1.0f - tanhf(h * h);
    }
    if (t2 >= 64 && t2 < 80) {
        int c = t2 - 64;
        codes[c] = event_code[tok * CC + c];
        mcode[c] = mask_code[tok * CC + c];
    }
    __syncthreads();

    float acc0 = bias_emb[d]     + time_b[d];
    float acc1 = bias_emb[d + 1] + time_b[d + 1];
    #pragma unroll
    for (int c = 0; c < CC; ++c) {
        unsigned pk = *(const unsigned*)&emb16[(long)codes[c] * DD + d];
        acc0 += bf2f((u16)(pk & 0xffffu)) * mcode[c];
        acc1 += bf2f((u16)(pk >> 16))     * mcode[c];
    }
    #pragma unroll 8
    for (int j = 0; j < 64; ++j) {
        float2 tw = *(const float2*)&time_W[j * DD + d];
        acc0 += f[j] * tw.x;
        acc1 += f[j] * tw.y;
    }

    int pos = s + 1;
    if (pos <= input_len[b]) {
        int p = pos - 1;
        float e    = (float)d * (1.0f / 512.0f);     // d even
        float invf = exp2f(-13.287712379549449f * e); // 10000^-e
        float ang  = (float)p * invf;
        acc0 += sinf(ang);
        acc1 += cosf(ang);
    }
    long o = (long)tok * DD + d;
    float2 o2; o2.x = acc0; o2.y = acc1;
    *(float2*)&out[o] = o2;
    unsigned pk = (unsigned)f2bf(acc0) | ((unsigned)f2bf(acc1) << 16);
    *(unsigned*)&oh[o] = pk;
}

// ---------------------------------------------------------------------------
// Kernel 2: MFMA GEMM, 2-phase double-buffered pipeline (T3-minimum).
// C = A_bf16[M,K] @ (Bh+Bl)^T[N,K], 2 MFMA per frag pair. BM=128, BK=32.
// Raw s_barrier (no vmcnt drain); counted vmcnt keeps next tile in flight
// under MFMA. XCD swizzle: all n-blocks of an M-panel on one XCD.
// EMIT: 0 = fp32, 2 = bf16. SEG3: split output cols into 3 [*,512] buffers.
// ---------------------------------------------------------------------------
template<int BN, bool RELU, bool RES, int EMIT, bool SEG3>
__global__ __launch_bounds__(256) void mgemm(
    const u16* __restrict__ A,
    const u16* __restrict__ Bh, const u16* __restrict__ Bl,
    const float* __restrict__ bias0, const float* __restrict__ bias1,
    const float* __restrict__ bias2,
    const float* __restrict__ res,
    float* __restrict__ C,
    u16* __restrict__ O0, u16* __restrict__ O1, u16* __restrict__ O2,
    int N, int K)
{
    constexpr int WN  = BN / 2;
    constexpr int NI  = WN / 16;
    constexpr int LPW = 2 + 2 * (BN / 64);   // gload_lds per wave per tile
    __shared__ __align__(16) u16 A_s[2][128 * 32];
    __shared__ __align__(16) u16 Bh_s[2][BN * 32];
    __shared__ __align__(16) u16 Bl_s[2][BN * 32];

    const int tid  = threadIdx.x;
    const int wid  = tid >> 6, lane = tid & 63;
    const int wr   = wid >> 1, wc = wid & 1;
    const int l4   = lane >> 4, l15 = lane & 15;

    // XCD swizzle (nwg % 8 == 0 in all our grids)
    const int bid  = blockIdx.x + gridDim.x * blockIdx.y;
    const int xcd  = bid & 7;
    const int slot = bid >> 3;
    const int ppx  = gridDim.y >> 3;
    const int by   = xcd * ppx + slot / gridDim.x;
    const int bx   = slot % gridDim.x;
    const int m0   = by * 128, n0 = bx * BN;
    const int sr   = lane >> 2, sc = lane & 3;

    auto STAGE = [&](int bufi, int k0) {
        #pragma unroll
        for (int i = 0; i < 2; ++i) {
            int rr = wid * 32 + i * 16;
            long go = (long)(m0 + rr + sr) * K + k0 + sc * 8;
            gload16(A + go, &A_s[bufi][rr * 32]);
        }
        #pragma unroll
        for (int i = 0; i < BN / 64; ++i) {
            int rr = wid * (BN / 4) + i * 16;
            long go = (long)(n0 + rr + sr) * K + k0 + sc * 8;
            gload16(Bh + go, &Bh_s[bufi][rr * 32]);
            gload16(Bl + go, &Bl_s[bufi][rr * 32]);
        }
    };

    f32x4 acc[4][NI];
    #pragma unroll
    for (int mi = 0; mi < 4; ++mi)
        #pragma unroll
        for (int ni = 0; ni < NI; ++ni)
            acc[mi][ni] = (f32x4){0.f, 0.f, 0.f, 0.f};

    STAGE(0, 0);
    const int nt = K / 32;
    for (int t = 0; t < nt; ++t) {
        const int cur = t & 1;
        if (t + 1 < nt) {
            STAGE(cur ^ 1, (t + 1) * 32);
            asm volatile("s_waitcnt vmcnt(%0)" :: "i"(LPW) : "memory");
        } else {
            asm volatile("s_waitcnt vmcnt(0)" ::: "memory");
        }
        __builtin_amdgcn_s_barrier();   // current tile fully resident

        bf16x8 af[4], bh[NI], bl[NI];
        #pragma unroll
        for (int mi = 0; mi < 4; ++mi) {
            int row = wr * 64 + mi * 16 + l15;
            af[mi] = *(const bf16x8*)&A_s[cur][row * 32 + l4 * 8];
        }
        #pragma unroll
        for (int ni = 0; ni < NI; ++ni) {
            int row = wc * WN + ni * 16 + l15;
            bh[ni] = *(const bf16x8*)&Bh_s[cur][row * 32 + l4 * 8];
            bl[ni] = *(const bf16x8*)&Bl_s[cur][row * 32 + l4 * 8];
        }
        asm volatile("s_waitcnt lgkmcnt(0)" ::: "memory");
        __builtin_amdgcn_sched_barrier(0);
        __builtin_amdgcn_s_barrier();   // all reads done -> buffer reusable

        #pragma unroll
        for (int mi = 0; mi < 4; ++mi)
            #pragma unroll
            for (int ni = 0; ni < NI; ++ni) {
                acc[mi][ni] = __builtin_amdgcn_mfma_f32_16x16x32_bf16(af[mi], bh[ni], acc[mi][ni], 0, 0, 0);
                acc[mi][ni] = __builtin_amdgcn_mfma_f32_16x16x32_bf16(af[mi], bl[ni], acc[mi][ni], 0, 0, 0);
            }
    }

    // epilogue: C/D frag mapping col = lane&15, row = (lane>>4)*4 + reg
    #pragma unroll
    for (int mi = 0; mi < 4; ++mi)
        #pragma unroll
        for (int ni = 0; ni < NI; ++ni) {
            int colg = n0 + wc * WN + ni * 16 + l15;
            int seg  = SEG3 ? (colg >> 9) : 0;
            int coll = SEG3 ? (colg & 511) : colg;
            const float* bp = SEG3 ? (seg == 0 ? bias0 : seg == 1 ? bias1 : bias2) : bias0;
            u16* op = SEG3 ? (seg == 0 ? O0 : seg == 1 ? O1 : O2) : O0;
            const int ost = SEG3 ? 512 : N;
            float bv = bp[coll];
            #pragma unroll
            for (int r = 0; r < 4; ++r) {
                int row = m0 + wr * 64 + mi * 16 + l4 * 4 + r;
                long off = (long)row * ost + coll;
                float v = acc[mi][ni][r] + bv;
                if (RES) v += res[off];
                if (RELU) v = fmaxf(v, 0.f);
                if (EMIT == 2) op[off] = f2bf(v);
                else           C[off]  = v;
            }
        }
}

// ---------------------------------------------------------------------------
// Kernel 3: MFMA flash-attention over 128 contiguous [512x64] slabs.
// XCD-swizzled so a group's 8 query-tile blocks share one XCD's L2.
// ---------------------------------------------------------------------------
__global__ __launch_bounds__(256) void attn_kernel(
    const u16* __restrict__ Qg, const u16* __restrict__ Kg, const u16* __restrict__ Vg,
    u16* __restrict__ Oh)
{
    const int bid = blockIdx.x;
    const int xcd = bid & 7, slot = bid >> 3;      // 1024 blocks
    const int g   = xcd * 16 + (slot >> 3);        // 16 groups per XCD
    const int qt  = slot & 7;
    const int tid = threadIdx.x;
    const int w   = tid >> 6;
    const int lane = tid & 63;
    const int l4  = lane >> 4, l15 = lane & 15;

    __shared__ __align__(16) u16 Qs[64 * ST];
    __shared__ __align__(16) u16 Ks[64 * ST];
    __shared__ __align__(16) u16 Vt[64 * ST];   // V^T: [d][k]
    __shared__ __align__(16) u16 Ps[64 * ST];   // P:   [q][k]

    const long gbase = (long)g * GRP;

    {
        const u16* src = Qg + gbase + (long)qt * 64 * 64;
        #pragma unroll
        for (int i = 0; i < 2; ++i) {
            int slot2 = tid + i * 256;
            int row = slot2 >> 3, c8 = slot2 & 7;
            *(int4*)&Qs[row * ST + c8 * 8] = *(const int4*)&src[row * 64 + c8 * 8];
        }
    }
    __syncthreads();

    const bf16x8 qf0 = *(const bf16x8*)&Qs[(w * 16 + l15) * ST + l4 * 8];
    const bf16x8 qf1 = *(const bf16x8*)&Qs[(w * 16 + l15) * ST + 32 + l4 * 8];

    f32x4 oacc[4];
    #pragma unroll
    for (int db = 0; db < 4; ++db) oacc[db] = (f32x4){0.f, 0.f, 0.f, 0.f};
    float mrun = -3e38f, lrun = 0.f;

    const int k0t = (tid >> 4) * 4;
    const int d0t = (tid & 15) * 4;

    for (int kt = 0; kt < 8; ++kt) {
        const u16* ksrc = Kg + gbase + (long)kt * 4096;
        const u16* vsrc = Vg + gbase + (long)kt * 4096;
        #pragma unroll
        for (int i = 0; i < 2; ++i) {
            int slot2 = tid + i * 256;
            int row = slot2 >> 3, c8 = slot2 & 7;
            *(int4*)&Ks[row * ST + c8 * 8] = *(const int4*)&ksrc[row * 64 + c8 * 8];
        }
        {   // V 4x4 register transpose -> Vt[d][k]
            ushort4 r0 = *(const ushort4*)&vsrc[(k0t + 0) * 64 + d0t];
            ushort4 r1 = *(const ushort4*)&vsrc[(k0t + 1) * 64 + d0t];
            ushort4 r2 = *(const ushort4*)&vsrc[(k0t + 2) * 64 + d0t];
            ushort4 r3 = *(const ushort4*)&vsrc[(k0t + 3) * 64 + d0t];
            ushort4 t0, t1, t2, t3;
            t0.x = r0.x; t0.y = r1.x; t0.z = r2.x; t0.w = r3.x;
            t1.x = r0.y; t1.y = r1.y; t1.z = r2.y; t1.w = r3.y;
            t2.x = r0.z; t2.y = r1.z; t2.z = r2.z; t2.w = r3.z;
            t3.x = r0.w; t3.y = r1.w; t3.z = r2.w; t3.w = r3.w;
            *(ushort4*)&Vt[(d0t + 0) * ST + k0t] = t0;
            *(ushort4*)&Vt[(d0t + 1) * ST + k0t] = t1;
            *(ushort4*)&Vt[(d0t + 2) * ST + k0t] = t2;
            *(ushort4*)&Vt[(d0t + 3) * ST + k0t] = t3;
        }
        __syncthreads();

        f32x4 sacc[4];
        #pragma unroll
        for (int kb = 0; kb < 4; ++kb) {
            bf16x8 a0 = *(const bf16x8*)&Ks[(kb * 16 + l15) * ST + l4 * 8];
            bf16x8 a1 = *(const bf16x8*)&Ks[(kb * 16 + l15) * ST + 32 + l4 * 8];
            f32x4 z = (f32x4){0.f, 0.f, 0.f, 0.f};
            z = __builtin_amdgcn_mfma_f32_16x16x32_bf16(a0, qf0, z, 0, 0, 0);
            z = __builtin_amdgcn_mfma_f32_16x16x32_bf16(a1, qf1, z, 0, 0, 0);
            sacc[kb] = z;
        }

        float pm = -3e38f;
        #pragma unroll
        for (int kb = 0; kb < 4; ++kb)
            #pragma unroll
            for (int r = 0; r < 4; ++r)
                pm = fmaxf(pm, sacc[kb][r]);
        pm *= 0.125f;
        pm = fmaxf(pm, __shfl_xor(pm, 16));
        pm = fmaxf(pm, __shfl_xor(pm, 32));
        float mn   = fmaxf(mrun, pm);
        float corr = __expf(mrun - mn);
        float psum = 0.f;
        u16 pb[16];
        #pragma unroll
        for (int kb = 0; kb < 4; ++kb)
            #pragma unroll
            for (int r = 0; r < 4; ++r) {
                float p = __expf(sacc[kb][r] * 0.125f - mn);
                u16 b = f2bf(p);
                pb[kb * 4 + r] = b;
                psum += bf2f(b);
            }
        psum += __shfl_xor(psum, 16);
        psum += __shfl_xor(psum, 32);
        lrun = lrun * corr + psum;
        mrun = mn;

        #pragma unroll
        for (int kb = 0; kb < 4; ++kb)
            #pragma unroll
            for (int r = 0; r < 4; ++r)
                Ps[(w * 16 + l15) * ST + kb * 16 + l4 * 4 + r] = pb[kb * 4 + r];

        float cr[4];
        #pragma unroll
        for (int r = 0; r < 4; ++r) cr[r] = __shfl(corr, l4 * 4 + r);
        #pragma unroll
        for (int db = 0; db < 4; ++db)
            #pragma unroll
            for (int r = 0; r < 4; ++r)
                oacc[db][r] *= cr[r];

        asm volatile("s_waitcnt lgkmcnt(0)" ::: "memory");
        __builtin_amdgcn_sched_barrier(0);
        bf16x8 pa0 = *(const bf16x8*)&Ps[(w * 16 + l15) * ST + l4 * 8];
        bf16x8 pa1 = *(const bf16x8*)&Ps[(w * 16 + l15) * ST + 32 + l4 * 8];
        #pragma unroll
        for (int db = 0; db < 4; ++db) {
            bf16x8 v0 = *(const bf16x8*)&Vt[(db * 16 + l15) * ST + l4 * 8];
            bf16x8 v1 = *(const bf16x8*)&Vt[(db * 16 + l15) * ST + 32 + l4 * 8];
            oacc[db] = __builtin_amdgcn_mfma_f32_16x16x32_bf16(pa0, v0, oacc[db], 0, 0, 0);
            oacc[db] = __builtin_amdgcn_mfma_f32_16x16x32_bf16(pa1, v1, oacc[db], 0, 0, 0);
        }
        __syncthreads();
    }

    float li[4];
    #pragma unroll
    for (int r = 0; r < 4; ++r) li[r] = 1.0f / __shfl(lrun, l4 * 4 + r);
    #pragma unroll
    for (int db = 0; db < 4; ++db)
        #pragma unroll
        for (int r = 0; r < 4; ++r) {
            float val = oacc[db][r] * li[r];
            long addr = gbase + (long)(qt * 64 + w * 16 + l4 * 4 + r) * 64 + db * 16 + l15;
            Oh[addr] = f2bf(val);
        }
}

// ---------------------------------------------------------------------------
// Kernel 4: LayerNorm over D=512; emits fp32 + bf16
// ---------------------------------------------------------------------------
__global__ __launch_bounds__(256) void ln_kernel(
    const float* __restrict__ X,
    const float* __restrict__ gam,
    const float* __restrict__ bet,
    float* __restrict__ Y, u16* __restrict__ Yh,
    float eps)
{
    const int row = blockIdx.x;
    const int tid = threadIdx.x;
    const float* x = X + (long)row * DD;

    float x0 = x[tid], x1 = x[tid + 256];
    __shared__ float ws4[4];
    const int wid = tid >> 6, lane = tid & 63;

    float sum = x0 + x1;
    #pragma unroll
    for (int off = 32; off > 0; off >>= 1) sum += __shfl_down(sum, off, 64);
    if (lane == 0) ws4[wid] = sum;
    __syncthreads();
    float mean = (ws4[0] + ws4[1] + ws4[2] + ws4[3]) * (1.0f / 512.0f);
    __syncthreads();

    float d0 = x0 - mean, d1 = x1 - mean;
    float s2 = d0 * d0 + d1 * d1;
    #pragma unroll
    for (int off = 32; off > 0; off >>= 1) s2 += __shfl_down(s2, off, 64);
    if (lane == 0) ws4[wid] = s2;
    __syncthreads();
    float var = (ws4[0] + ws4[1] + ws4[2] + ws4[3]) * (1.0f / 512.0f);
    float inv = rsqrtf(var + eps);

    float o0 = d0 * inv * gam[tid]       + bet[tid];
    float o1 = d1 * inv * gam[tid + 256] + bet[tid + 256];
    long b0 = (long)row * DD + tid;
    Y[b0] = o0;  Y[b0 + 256] = o1;
    Yh[b0] = f2bf(o0);
    Yh[b0 + 256] = f2bf(o1);
}

// ---------------------------------------------------------------------------
extern "C" void kernel_launch(void* const* d_in, const int* in_sizes, int n_in,
                              void* d_out, int out_size, void* d_ws, size_t ws_size,
                              hipStream_t stream)
{
    const int*   event_code = (const int*)  d_in[0];
    const float* mask_code  = (const float*)d_in[2];
    const float* seq_time   = (const float*)d_in[3];
    const int*   input_len  = (const int*)  d_in[6];
    const float* emb        = (const float*)d_in[7];
    const float* bias_emb   = (const float*)d_in[8];
    const float* sel_W      = (const float*)d_in[9];
    const float* sel_b      = (const float*)d_in[10];
    const float* time_W     = (const float*)d_in[11];
    const float* time_b     = (const float*)d_in[12];
    const float* Wq  = (const float*)d_in[13];
    const float* bq  = (const float*)d_in[14];
    const float* Wk  = (const float*)d_in[15];
    const float* bk  = (const float*)d_in[16];
    const float* Wv  = (const float*)d_in[17];
    const float* bv  = (const float*)d_in[18];
    const float* Wo  = (const float*)d_in[19];
    const float* bo  = (const float*)d_in[20];
    const float* ln1g = (const float*)d_in[21];
    const float* ln1b = (const float*)d_in[22];
    const float* W1  = (const float*)d_in[23];
    const float* b1  = (const float*)d_in[24];
    const float* W2  = (const float*)d_in[25];
    const float* b2  = (const float*)d_in[26];
    const float* ln2g = (const float*)d_in[27];
    const float* ln2b = (const float*)d_in[28];

    float* ws = (float*)d_ws;
    const long ND = (long)NTOK * DD;      // 4.19M elems
    const long NF = (long)NTOK * FF;
    float* x = ws;                        // fp32 residual
    float* y = ws + ND;
    u16* q16 = (u16*)(ws + 2 * ND);       // bf16 QKV
    u16* k16 = q16 + ND;
    u16* v16 = k16 + ND;
    u16* a16 = v16 + ND;                  // bf16 activations
    u16* h16 = a16 + ND;                  // FFN hidden bf16
    u16* e16 = h16 + NF;                  // bf16 embedding table [V,512]
    u16* wqkv_h = e16 + (long)VV * DD;    // packed QKV weights [L][1536][512]
    const long SZ3 = (long)LL * 1536 * DD;
    const long SZQ = (long)LL * DD * DD, SZF = (long)LL * DD * FF;
    u16* wqkv_l = wqkv_h + SZ3;
    u16* wo_h = wqkv_l + SZ3;  u16* wo_l = wo_h + SZQ;
    u16* w1_h = wo_l + SZQ;    u16* w1_l = w1_h + SZF;
    u16* w2_h = w1_l + SZF;    u16* w2_l = w2_h + SZF;

    cvt_qkvo<<<dim3(16, 16, 8), 256, 0, stream>>>(Wq, Wk, Wv, Wo, wqkv_h, wqkv_l, wo_h, wo_l);
    cvt_weight<<<dim3(FF/32, DD/32, LL), 256, 0, stream>>>(W1, w1_h, w1_l, DD, FF);
    cvt_weight<<<dim3(DD/32, FF/32, LL), 256, 0, stream>>>(W2, w2_h, w2_l, FF, DD);
    cvt_emb<<<(VV * DD) / 1024, 256, 0, stream>>>(emb, e16);

    embed_kernel<<<NTOK, 256, 0, stream>>>(event_code, mask_code, seq_time, input_len,
                                           e16, bias_emb, sel_W, sel_b, time_W, time_b,
                                           x, a16);

    const dim3 gQKV(1536 / 64, NTOK / 128);  // (24,64) = 1536 blocks
    const dim3 gN512(DD / 64, NTOK / 128);   // (8,64)  = 512 blocks
    const dim3 gN2048(FF / 128, NTOK / 128); // (16,64) = 1024 blocks

    for (int l = 0; l < LL; ++l) {
        const u16* qkvh = wqkv_h + (long)l * 1536 * DD;
        const u16* qkvl = wqkv_l + (long)l * 1536 * DD;
        const u16* oh = wo_h + (long)l * DD * DD;  const u16* ol = wo_l + (long)l * DD * DD;
        const u16* f1h = w1_h + (long)l * DD * FF; const u16* f1l = w1_l + (long)l * DD * FF;
        const u16* f2h = w2_h + (long)l * FF * DD; const u16* f2l = w2_l + (long)l * FF * DD;

        // merged QKV projection -> bf16 q16/k16/v16
        mgemm<64,false,false,2,true><<<gQKV, 256, 0, stream>>>(
            a16, qkvh, qkvl, bq + l*DD, bk + l*DD, bv + l*DD, nullptr,
            nullptr, q16, k16, v16, 1536, DD);

        // ctx (bf16) into a16
        attn_kernel<<<NG * 8, 256, 0, stream>>>(q16, k16, v16, a16);

        // y = x + ctx@Wo + bo ; LN1 (eps 1e-3)
        mgemm<64,false,true,0,false><<<gN512, 256, 0, stream>>>(
            a16, oh, ol, bo + l*DD, nullptr, nullptr, x,
            y, nullptr, nullptr, nullptr, DD, DD);
        ln_kernel<<<NTOK, 256, 0, stream>>>(y, ln1g + l*DD, ln1b + l*DD, y, a16, 1e-3f);

        // h = relu(y@W1 + b1) -> bf16
        mgemm<128,true,false,2,false><<<gN2048, 256, 0, stream>>>(
            a16, f1h, f1l, b1 + l*FF, nullptr, nullptr, nullptr,
            nullptr, h16, nullptr, nullptr, FF, DD);
        // x = y + h@W2 + b2 ; LN2 (eps 1e-6)
        mgemm<64,false,true,0,false><<<gN512, 256, 0, stream>>>(
            h16, f2h, f2l, b2 + l*DD, nullptr, nullptr, y,
            x, nullptr, nullptr, nullptr, DD, FF);

        float* lnout = (l == LL - 1) ? (float*)d_out : x;
        ln_kernel<<<NTOK, 256, 0, stream>>>(x, ln2g + l*DD, ln2b + l*DD, lnout, a16, 1e-6f);
    }
}

// Round 7
// 560.956 us; speedup vs baseline: 4.2504x; 1.0629x over previous
//
#include <hip/hip_runtime.h>
#include <math.h>

// Problem constants
#define BB   16
#define SS   512
#define CC   16
#define DD   512
#define DH   64
#define FF   2048
#define LL   2
#define VV   20000
#define NTOK (BB*SS)      // 8192
#define NG   (BB*8)       // 128 attention groups
#define GRP  (SS*DH)      // 32768 elems per attention group slab
#define ST   72           // padded LDS row stride (u16) for attn tiles

typedef unsigned short u16;
typedef __attribute__((ext_vector_type(8))) short bf16x8;
typedef __attribute__((ext_vector_type(4))) float f32x4;

__device__ __forceinline__ u16 f2bf(float x) {
    unsigned u = __float_as_uint(x);
    u = (u + 0x7fffu + ((u >> 16) & 1u)) >> 16;
    return (u16)u;
}
__device__ __forceinline__ float bf2f(u16 h) {
    return __uint_as_float(((unsigned)h) << 16);
}
__device__ __forceinline__ void gload16(const void* g, void* l) {
    __builtin_amdgcn_global_load_lds((const __attribute__((address_space(1))) void*)g,
                                     (__attribute__((address_space(3))) void*)l, 16, 0, 0);
}

// ---------------------------------------------------------------------------
// Kernel 0a: fused transpose+split for Wq/Wk/Wv/Wo.  QKV rows packed into one
// [L][1536][512] B-matrix (k-contiguous); Wo into [L][512][512].
// grid (16,16,8): z = which*2 + layer
// ---------------------------------------------------------------------------
__global__ __launch_bounds__(256) void cvt_qkvo(
    const float* __restrict__ Wq, const float* __restrict__ Wk,
    const float* __restrict__ Wv, const float* __restrict__ Wo,
    u16* __restrict__ qkv_h, u16* __restrict__ qkv_l,
    u16* __restrict__ o_h,   u16* __restrict__ o_l)
{
    const int z = blockIdx.z;
    const int which = z >> 1, l = z & 1;
    const float* W = (which == 0) ? Wq : (which == 1) ? Wk : (which == 2) ? Wv : Wo;
    W += (long)l * DD * DD;
    u16 *Th, *Tl;
    if (which < 3) {
        long off = (long)l * 1536 * DD + (long)which * DD * DD;
        Th = qkv_h + off; Tl = qkv_l + off;
    } else {
        long off = (long)l * DD * DD;
        Th = o_h + off;   Tl = o_l + off;
    }
    const int n0 = blockIdx.x * 32, k0 = blockIdx.y * 32;
    __shared__ float T[32][33];
    const int t = threadIdx.x;
    {
        const int lk = t >> 3, ln4 = (t & 7) * 4;
        float4 w4 = *(const float4*)&W[(long)(k0 + lk) * DD + n0 + ln4];
        T[ln4 + 0][lk] = w4.x; T[ln4 + 1][lk] = w4.y;
        T[ln4 + 2][lk] = w4.z; T[ln4 + 3][lk] = w4.w;
    }
    __syncthreads();
    {
        const int nn = t >> 3, kq = (t & 7) * 4;
        float v0 = T[nn][kq + 0], v1 = T[nn][kq + 1];
        float v2 = T[nn][kq + 2], v3 = T[nn][kq + 3];
        ushort4 hh, ll;
        hh.x = f2bf(v0); ll.x = f2bf(v0 - bf2f(hh.x));
        hh.y = f2bf(v1); ll.y = f2bf(v1 - bf2f(hh.y));
        hh.z = f2bf(v2); ll.z = f2bf(v2 - bf2f(hh.z));
        hh.w = f2bf(v3); ll.w = f2bf(v3 - bf2f(hh.w));
        long o = (long)(n0 + nn) * DD + k0 + kq;
        *(ushort4*)&Th[o] = hh;
        *(ushort4*)&Tl[o] = ll;
    }
}

// ---------------------------------------------------------------------------
// Kernel 0b: generic transpose+split (W1, W2). grid (N/32, K/32, L)
// ---------------------------------------------------------------------------
__global__ __launch_bounds__(256) void cvt_weight(
    const float* __restrict__ W, u16* __restrict__ Th, u16* __restrict__ Tl,
    int K, int N)
{
    const long moff = (long)blockIdx.z * K * N;
    W += moff; Th += moff; Tl += moff;
    const int n0 = blockIdx.x * 32, k0 = blockIdx.y * 32;
    __shared__ float T[32][33];
    const int t = threadIdx.x;
    {
        const int lk = t >> 3, ln4 = (t & 7) * 4;
        float4 w4 = *(const float4*)&W[(long)(k0 + lk) * N + n0 + ln4];
        T[ln4 + 0][lk] = w4.x; T[ln4 + 1][lk] = w4.y;
        T[ln4 + 2][lk] = w4.z; T[ln4 + 3][lk] = w4.w;
    }
    __syncthreads();
    {
        const int nn = t >> 3, kq = (t & 7) * 4;
        float v0 = T[nn][kq + 0], v1 = T[nn][kq + 1];
        float v2 = T[nn][kq + 2], v3 = T[nn][kq + 3];
        ushort4 hh, ll;
        hh.x = f2bf(v0); ll.x = f2bf(v0 - bf2f(hh.x));
        hh.y = f2bf(v1); ll.y = f2bf(v1 - bf2f(hh.y));
        hh.z = f2bf(v2); ll.z = f2bf(v2 - bf2f(hh.z));
        hh.w = f2bf(v3); ll.w = f2bf(v3 - bf2f(hh.w));
        long o = (long)(n0 + nn) * K + k0 + kq;
        *(ushort4*)&Th[o] = hh;
        *(ushort4*)&Tl[o] = ll;
    }
}

// ---------------------------------------------------------------------------
// Kernel 0c: embedding table fp32 -> bf16 (10.24M elems, 10000 blocks)
// ---------------------------------------------------------------------------
__global__ __launch_bounds__(256) void cvt_emb(const float* __restrict__ E,
                                               u16* __restrict__ E16)
{
    long i = ((long)blockIdx.x * 256 + threadIdx.x) * 4;
    float4 v = *(const float4*)&E[i];
    ushort4 o;
    o.x = f2bf(v.x); o.y = f2bf(v.y); o.z = f2bf(v.z); o.w = f2bf(v.w);
    *(ushort4*)&E16[i] = o;
}

// ---------------------------------------------------------------------------
// Kernel 1: embedding sum + time MLP + PE.  8 tokens per block (grid 1024),
// 256 threads x 2 dims. time_W read ONCE per block (GEMM-style reuse over
// the 8 tokens) -> kills the 1 GB L2 re-read that made R6's embed slow.
// ---------------------------------------------------------------------------
__global__ __launch_bounds__(256) void embed_kernel(
    const int*   __restrict__ event_code,
    const float* __restrict__ mask_code,
    const float* __restrict__ seq_time,
    const int*   __restrict__ input_len,
    const u16*   __restrict__ emb16,
    const float* __restrict__ bias_emb,
    const float* __restrict__ sel_W,
    const float* __restrict__ sel_b,
    const float* __restrict__ time_W,
    const float* __restrict__ time_b,
    float* __restrict__ out, u16* __restrict__ oh)
{
    const int tok0 = blockIdx.x * 8;
    const int b    = tok0 >> 9;          // 8 | 512 -> same batch row per block
    const int t2   = threadIdx.x;        // 0..255
    const int d    = t2 * 2;

    __shared__ int   codes_s[8][16];
    __shared__ float mcode_s[8][16];
    __shared__ float f_s[64][8];         // [j][tok]
    __shared__ float tvals[8];

    if (t2 < 128) {
        int tok = t2 >> 4, c = t2 & 15;
        codes_s[tok][c] = event_code[(tok0 + tok) * CC + c];
        mcode_s[tok][c] = mask_code[(tok0 + tok) * CC + c];
    }
    if (t2 < 8) tvals[t2] = seq_time[tok0 + t2] * (1.0f / 7200.0f);
    __syncthreads();

    {   // f[j][tok] = 1 - tanh((t*selW[j]+selb[j])^2); 2 values per thread
        int tok = t2 >> 5;               // 0..7
        int j0  = (t2 & 31) * 2;         // 0..62
        float t = tvals[tok];
        #pragma unroll
        for (int i = 0; i < 2; ++i) {
            int j = j0 + i;
            float h = t * sel_W[j] + sel_b[j];
            f_s[j][tok] = 1.0f - tanhf(h * h);
        }
    }
    __syncthreads();

    float be0 = bias_emb[d]     + time_b[d];
    float be1 = bias_emb[d + 1] + time_b[d + 1];
    float2 acc[8];
    #pragma unroll
    for (int tok = 0; tok < 8; ++tok) { acc[tok].x = be0; acc[tok].y = be1; }

    // gather: 8 tok x 16 codes = 128 packed-bf16 dword loads, deep ILP
    #pragma unroll 2
    for (int c = 0; c < CC; ++c) {
        #pragma unroll
        for (int tok = 0; tok < 8; ++tok) {
            unsigned pk = *(const unsigned*)&emb16[(long)codes_s[tok][c] * DD + d];
            float mc = mcode_s[tok][c];
            acc[tok].x += bf2f((u16)(pk & 0xffffu)) * mc;
            acc[tok].y += bf2f((u16)(pk >> 16))     * mc;
        }
    }

    // time projection: each time_W element read once per block
    #pragma unroll 4
    for (int j = 0; j < 64; ++j) {
        float2 tw = *(const float2*)&time_W[j * DD + d];
        float4 f0 = *(const float4*)&f_s[j][0];
        float4 f1 = *(const float4*)&f_s[j][4];
        float fv[8] = {f0.x, f0.y, f0.z, f0.w, f1.x, f1.y, f1.z, f1.w};
        #pragma unroll
        for (int tok = 0; tok < 8; ++tok) {
            acc[tok].x += fv[tok] * tw.x;
            acc[tok].y += fv[tok] * tw.y;
        }
    }

    // positional encoding (d even -> e uses d directly)
    float e    = (float)d * (1.0f / 512.0f);
    float invf = exp2f(-13.287712379549449f * e);   // 10000^-e
    int ilen = input_len[b];
    #pragma unroll
    for (int tok = 0; tok < 8; ++tok) {
        int s = (tok0 + tok) & 511;
        if (s + 1 <= ilen) {
            float ang = (float)s * invf;
            acc[tok].x += sinf(ang);
            acc[tok].y += cosf(ang);
        }
    }

    #pragma unroll
    for (int tok = 0; tok < 8; ++tok) {
        long o = (long)(tok0 + tok) * DD + d;
        *(float2*)&out[o] = acc[tok];
        unsigned pk = (unsigned)f2bf(acc[tok].x) | ((unsigned)f2bf(acc[tok].y) << 16);
        *(unsigned*)&oh[o] = pk;
    }
}

// ---------------------------------------------------------------------------
// Kernel 2: MFMA GEMM, 2-phase double-buffered pipeline.
// C = A_bf16[M,K] @ (Bh+Bl)^T[N,K], 2 MFMA per frag pair. BM=128, BK=32.
// EMIT: 0 = fp32, 2 = bf16. SEG3: split output cols into 3 [*,512] buffers.
// ---------------------------------------------------------------------------
template<int BN, bool RELU, bool RES, int EMIT, bool SEG3>
__global__ __launch_bounds__(256) void mgemm(
    const u16* __restrict__ A,
    const u16* __restrict__ Bh, const u16* __restrict__ Bl,
    const float* __restrict__ bias0, const float* __restrict__ bias1,
    const float* __restrict__ bias2,
    const float* __restrict__ res,
    float* __restrict__ C,
    u16* __restrict__ O0, u16* __restrict__ O1, u16* __restrict__ O2,
    int N, int K)
{
    constexpr int WN  = BN / 2;
    constexpr int NI  = WN / 16;
    constexpr int LPW = 2 + 2 * (BN / 64);   // gload_lds per wave per tile
    __shared__ __align__(16) u16 A_s[2][128 * 32];
    __shared__ __align__(16) u16 Bh_s[2][BN * 32];
    __shared__ __align__(16) u16 Bl_s[2][BN * 32];

    const int tid  = threadIdx.x;
    const int wid  = tid >> 6, lane = tid & 63;
    const int wr   = wid >> 1, wc = wid & 1;
    const int l4   = lane >> 4, l15 = lane & 15;

    // XCD swizzle (nwg % 8 == 0 in all our grids)
    const int bid  = blockIdx.x + gridDim.x * blockIdx.y;
    const int xcd  = bid & 7;
    const int slot = bid >> 3;
    const int ppx  = gridDim.y >> 3;
    const int by   = xcd * ppx + slot / gridDim.x;
    const int bx   = slot % gridDim.x;
    const int m0   = by * 128, n0 = bx * BN;
    const int sr   = lane >> 2, sc = lane & 3;

    auto STAGE = [&](int bufi, int k0) {
        #pragma unroll
        for (int i = 0; i < 2; ++i) {
            int rr = wid * 32 + i * 16;
            long go = (long)(m0 + rr + sr) * K + k0 + sc * 8;
            gload16(A + go, &A_s[bufi][rr * 32]);
        }
        #pragma unroll
        for (int i = 0; i < BN / 64; ++i) {
            int rr = wid * (BN / 4) + i * 16;
            long go = (long)(n0 + rr + sr) * K + k0 + sc * 8;
            gload16(Bh + go, &Bh_s[bufi][rr * 32]);
            gload16(Bl + go, &Bl_s[bufi][rr * 32]);
        }
    };

    f32x4 acc[4][NI];
    #pragma unroll
    for (int mi = 0; mi < 4; ++mi)
        #pragma unroll
        for (int ni = 0; ni < NI; ++ni)
            acc[mi][ni] = (f32x4){0.f, 0.f, 0.f, 0.f};

    STAGE(0, 0);
    const int nt = K / 32;
    for (int t = 0; t < nt; ++t) {
        const int cur = t & 1;
        if (t + 1 < nt) {
            STAGE(cur ^ 1, (t + 1) * 32);
            asm volatile("s_waitcnt vmcnt(%0)" :: "i"(LPW) : "memory");
        } else {
            asm volatile("s_waitcnt vmcnt(0)" ::: "memory");
        }
        __builtin_amdgcn_s_barrier();   // current tile fully resident

        bf16x8 af[4], bh[NI], bl[NI];
        #pragma unroll
        for (int mi = 0; mi < 4; ++mi) {
            int row = wr * 64 + mi * 16 + l15;
            af[mi] = *(const bf16x8*)&A_s[cur][row * 32 + l4 * 8];
        }
        #pragma unroll
        for (int ni = 0; ni < NI; ++ni) {
            int row = wc * WN + ni * 16 + l15;
            bh[ni] = *(const bf16x8*)&Bh_s[cur][row * 32 + l4 * 8];
            bl[ni] = *(const bf16x8*)&Bl_s[cur][row * 32 + l4 * 8];
        }
        asm volatile("s_waitcnt lgkmcnt(0)" ::: "memory");
        __builtin_amdgcn_sched_barrier(0);
        __builtin_amdgcn_s_barrier();   // all reads done -> buffer reusable

        #pragma unroll
        for (int mi = 0; mi < 4; ++mi)
            #pragma unroll
            for (int ni = 0; ni < NI; ++ni) {
                acc[mi][ni] = __builtin_amdgcn_mfma_f32_16x16x32_bf16(af[mi], bh[ni], acc[mi][ni], 0, 0, 0);
                acc[mi][ni] = __builtin_amdgcn_mfma_f32_16x16x32_bf16(af[mi], bl[ni], acc[mi][ni], 0, 0, 0);
            }
    }

    // epilogue: C/D frag mapping col = lane&15, row = (lane>>4)*4 + reg
    #pragma unroll
    for (int mi = 0; mi < 4; ++mi)
        #pragma unroll
        for (int ni = 0; ni < NI; ++ni) {
            int colg = n0 + wc * WN + ni * 16 + l15;
            int seg  = SEG3 ? (colg >> 9) : 0;
            int coll = SEG3 ? (colg & 511) : colg;
            const float* bp = SEG3 ? (seg == 0 ? bias0 : seg == 1 ? bias1 : bias2) : bias0;
            u16* op = SEG3 ? (seg == 0 ? O0 : seg == 1 ? O1 : O2) : O0;
            const int ost = SEG3 ? 512 : N;
            float bv = bp[coll];
            #pragma unroll
            for (int r = 0; r < 4; ++r) {
                int row = m0 + wr * 64 + mi * 16 + l4 * 4 + r;
                long off = (long)row * ost + coll;
                float v = acc[mi][ni][r] + bv;
                if (RES) v += res[off];
                if (RELU) v = fmaxf(v, 0.f);
                if (EMIT == 2) op[off] = f2bf(v);
                else           C[off]  = v;
            }
        }
}

// ---------------------------------------------------------------------------
// Kernel 3: MFMA flash-attention over 128 contiguous [512x64] slabs.
// XCD-swizzled so a group's 8 query-tile blocks share one XCD's L2.
// ---------------------------------------------------------------------------
__global__ __launch_bounds__(256) void attn_kernel(
    const u16* __restrict__ Qg, const u16* __restrict__ Kg, const u16* __restrict__ Vg,
    u16* __restrict__ Oh)
{
    const int bid = blockIdx.x;
    const int xcd = bid & 7, slot = bid >> 3;      // 1024 blocks
    const int g   = xcd * 16 + (slot >> 3);        // 16 groups per XCD
    const int qt  = slot & 7;
    const int tid = threadIdx.x;
    const int w   = tid >> 6;
    const int lane = tid & 63;
    const int l4  = lane >> 4, l15 = lane & 15;

    __shared__ __align__(16) u16 Qs[64 * ST];
    __shared__ __align__(16) u16 Ks[64 * ST];
    __shared__ __align__(16) u16 Vt[64 * ST];   // V^T: [d][k]
    __shared__ __align__(16) u16 Ps[64 * ST];   // P:   [q][k]

    const long gbase = (long)g * GRP;

    {
        const u16* src = Qg + gbase + (long)qt * 64 * 64;
        #pragma unroll
        for (int i = 0; i < 2; ++i) {
            int slot2 = tid + i * 256;
            int row = slot2 >> 3, c8 = slot2 & 7;
            *(int4*)&Qs[row * ST + c8 * 8] = *(const int4*)&src[row * 64 + c8 * 8];
        }
    }
    __syncthreads();

    const bf16x8 qf0 = *(const bf16x8*)&Qs[(w * 16 + l15) * ST + l4 * 8];
    const bf16x8 qf1 = *(const bf16x8*)&Qs[(w * 16 + l15) * ST + 32 + l4 * 8];

    f32x4 oacc[4];
    #pragma unroll
    for (int db = 0; db < 4; ++db) oacc[db] = (f32x4){0.f, 0.f, 0.f, 0.f};
    float mrun = -3e38f, lrun = 0.f;

    const int k0t = (tid >> 4) * 4;
    const int d0t = (tid & 15) * 4;

    for (int kt = 0; kt < 8; ++kt) {
        const u16* ksrc = Kg + gbase + (long)kt * 4096;
        const u16* vsrc = Vg + gbase + (long)kt * 4096;
        #pragma unroll
        for (int i = 0; i < 2; ++i) {
            int slot2 = tid + i * 256;
            int row = slot2 >> 3, c8 = slot2 & 7;
            *(int4*)&Ks[row * ST + c8 * 8] = *(const int4*)&ksrc[row * 64 + c8 * 8];
        }
        {   // V 4x4 register transpose -> Vt[d][k]
            ushort4 r0 = *(const ushort4*)&vsrc[(k0t + 0) * 64 + d0t];
            ushort4 r1 = *(const ushort4*)&vsrc[(k0t + 1) * 64 + d0t];
            ushort4 r2 = *(const ushort4*)&vsrc[(k0t + 2) * 64 + d0t];
            ushort4 r3 = *(const ushort4*)&vsrc[(k0t + 3) * 64 + d0t];
            ushort4 t0, t1, t2, t3;
            t0.x = r0.x; t0.y = r1.x; t0.z = r2.x; t0.w = r3.x;
            t1.x = r0.y; t1.y = r1.y; t1.z = r2.y; t1.w = r3.y;
            t2.x = r0.z; t2.y = r1.z; t2.z = r2.z; t2.w = r3.z;
            t3.x = r0.w; t3.y = r1.w; t3.z = r2.w; t3.w = r3.w;
            *(ushort4*)&Vt[(d0t + 0) * ST + k0t] = t0;
            *(ushort4*)&Vt[(d0t + 1) * ST + k0t] = t1;
            *(ushort4*)&Vt[(d0t + 2) * ST + k0t] = t2;
            *(ushort4*)&Vt[(d0t + 3) * ST + k0t] = t3;
        }
        __syncthreads();

        f32x4 sacc[4];
        #pragma unroll
        for (int kb = 0; kb < 4; ++kb) {
            bf16x8 a0 = *(const bf16x8*)&Ks[(kb * 16 + l15) * ST + l4 * 8];
            bf16x8 a1 = *(const bf16x8*)&Ks[(kb * 16 + l15) * ST + 32 + l4 * 8];
            f32x4 z = (f32x4){0.f, 0.f, 0.f, 0.f};
            z = __builtin_amdgcn_mfma_f32_16x16x32_bf16(a0, qf0, z, 0, 0, 0);
            z = __builtin_amdgcn_mfma_f32_16x16x32_bf16(a1, qf1, z, 0, 0, 0);
            sacc[kb] = z;
        }

        float pm = -3e38f;
        #pragma unroll
        for (int kb = 0; kb < 4; ++kb)
            #pragma unroll
            for (int r = 0; r < 4; ++r)
                pm = fmaxf(pm, sacc[kb][r]);
        pm *= 0.125f;
        pm = fmaxf(pm, __shfl_xor(pm, 16));
        pm = fmaxf(pm, __shfl_xor(pm, 32));
        float mn   = fmaxf(mrun, pm);
        float corr = __expf(mrun - mn);
        float psum = 0.f;
        u16 pb[16];
        #pragma unroll
        for (int kb = 0; kb < 4; ++kb)
            #pragma unroll
            for (int r = 0; r < 4; ++r) {
                float p = __expf(sacc[kb][r] * 0.125f - mn);
                u16 b = f2bf(p);
                pb[kb * 4 + r] = b;
                psum += bf2f(b);
            }
        psum += __shfl_xor(psum, 16);
        psum += __shfl_xor(psum, 32);
        lrun = lrun * corr + psum;
        mrun = mn;

        #pragma unroll
        for (int kb = 0; kb < 4; ++kb)
            #pragma unroll
            for (int r = 0; r < 4; ++r)
                Ps[(w * 16 + l15) * ST + kb * 16 + l4 * 4 + r] = pb[kb * 4 + r];

        float cr[4];
        #pragma unroll
        for (int r = 0; r < 4; ++r) cr[r] = __shfl(corr, l4 * 4 + r);
        #pragma unroll
        for (int db = 0; db < 4; ++db)
            #pragma unroll
            for (int r = 0; r < 4; ++r)
                oacc[db][r] *= cr[r];

        asm volatile("s_waitcnt lgkmcnt(0)" ::: "memory");
        __builtin_amdgcn_sched_barrier(0);
        bf16x8 pa0 = *(const bf16x8*)&Ps[(w * 16 + l15) * ST + l4 * 8];
        bf16x8 pa1 = *(const bf16x8*)&Ps[(w * 16 + l15) * ST + 32 + l4 * 8];
        #pragma unroll
        for (int db = 0; db < 4; ++db) {
            bf16x8 v0 = *(const bf16x8*)&Vt[(db * 16 + l15) * ST + l4 * 8];
            bf16x8 v1 = *(const bf16x8*)&Vt[(db * 16 + l15) * ST + 32 + l4 * 8];
            oacc[db] = __builtin_amdgcn_mfma_f32_16x16x32_bf16(pa0, v0, oacc[db], 0, 0, 0);
            oacc[db] = __builtin_amdgcn_mfma_f32_16x16x32_bf16(pa1, v1, oacc[db], 0, 0, 0);
        }
        __syncthreads();
    }

    float li[4];
    #pragma unroll
    for (int r = 0; r < 4; ++r) li[r] = 1.0f / __shfl(lrun, l4 * 4 + r);
    #pragma unroll
    for (int db = 0; db < 4; ++db)
        #pragma unroll
        for (int r = 0; r < 4; ++r) {
            float val = oacc[db][r] * li[r];
            long addr = gbase + (long)(qt * 64 + w * 16 + l4 * 4 + r) * 64 + db * 16 + l15;
            Oh[addr] = f2bf(val);
        }
}

// ---------------------------------------------------------------------------
// Kernel 4: LayerNorm over D=512; emits fp32 + bf16
// ---------------------------------------------------------------------------
__global__ __launch_bounds__(256) void ln_kernel(
    const float* __restrict__ X,
    const float* __restrict__ gam,
    const float* __restrict__ bet,
    float* __restrict__ Y, u16* __restrict__ Yh,
    float eps)
{
    const int row = blockIdx.x;
    const int tid = threadIdx.x;
    const float* x = X + (long)row * DD;

    float x0 = x[tid], x1 = x[tid + 256];
    __shared__ float ws4[4];
    const int wid = tid >> 6, lane = tid & 63;

    float sum = x0 + x1;
    #pragma unroll
    for (int off = 32; off > 0; off >>= 1) sum += __shfl_down(sum, off, 64);
    if (lane == 0) ws4[wid] = sum;
    __syncthreads();
    float mean = (ws4[0] + ws4[1] + ws4[2] + ws4[3]) * (1.0f / 512.0f);
    __syncthreads();

    float d0 = x0 - mean, d1 = x1 - mean;
    float s2 = d0 * d0 + d1 * d1;
    #pragma unroll
    for (int off = 32; off > 0; off >>= 1) s2 += __shfl_down(s2, off, 64);
    if (lane == 0) ws4[wid] = s2;
    __syncthreads();
    float var = (ws4[0] + ws4[1] + ws4[2] + ws4[3]) * (1.0f / 512.0f);
    float inv = rsqrtf(var + eps);

    float o0 = d0 * inv * gam[tid]       + bet[tid];
    float o1 = d1 * inv * gam[tid + 256] + bet[tid + 256];
    long b0 = (long)row * DD + tid;
    Y[b0] = o0;  Y[b0 + 256] = o1;
    Yh[b0] = f2bf(o0);
    Yh[b0 + 256] = f2bf(o1);
}

// ---------------------------------------------------------------------------
extern "C" void kernel_launch(void* const* d_in, const int* in_sizes, int n_in,
                              void* d_out, int out_size, void* d_ws, size_t ws_size,
                              hipStream_t stream)
{
    const int*   event_code = (const int*)  d_in[0];
    const float* mask_code  = (const float*)d_in[2];
    const float* seq_time   = (const float*)d_in[3];
    const int*   input_len  = (const int*)  d_in[6];
    const float* emb        = (const float*)d_in[7];
    const float* bias_emb   = (const float*)d_in[8];
    const float* sel_W      = (const float*)d_in[9];
    const float* sel_b      = (const float*)d_in[10];
    const float* time_W     = (const float*)d_in[11];
    const float* time_b     = (const float*)d_in[12];
    const float* Wq  = (const float*)d_in[13];
    const float* bq  = (const float*)d_in[14];
    const float* Wk  = (const float*)d_in[15];
    const float* bk  = (const float*)d_in[16];
    const float* Wv  = (const float*)d_in[17];
    const float* bv  = (const float*)d_in[18];
    const float* Wo  = (const float*)d_in[19];
    const float* bo  = (const float*)d_in[20];
    const float* ln1g = (const float*)d_in[21];
    const float* ln1b = (const float*)d_in[22];
    const float* W1  = (const float*)d_in[23];
    const float* b1  = (const float*)d_in[24];
    const float* W2  = (const float*)d_in[25];
    const float* b2  = (const float*)d_in[26];
    const float* ln2g = (const float*)d_in[27];
    const float* ln2b = (const float*)d_in[28];

    float* ws = (float*)d_ws;
    const long ND = (long)NTOK * DD;      // 4.19M elems
    const long NF = (long)NTOK * FF;
    float* x = ws;                        // fp32 residual
    float* y = ws + ND;
    u16* q16 = (u16*)(ws + 2 * ND);       // bf16 QKV
    u16* k16 = q16 + ND;
    u16* v16 = k16 + ND;
    u16* a16 = v16 + ND;                  // bf16 activations
    u16* h16 = a16 + ND;                  // FFN hidden bf16
    u16* e16 = h16 + NF;                  // bf16 embedding table [V,512]
    u16* wqkv_h = e16 + (long)VV * DD;    // packed QKV weights [L][1536][512]
    const long SZ3 = (long)LL * 1536 * DD;
    const long SZQ = (long)LL * DD * DD, SZF = (long)LL * DD * FF;
    u16* wqkv_l = wqkv_h + SZ3;
    u16* wo_h = wqkv_l + SZ3;  u16* wo_l = wo_h + SZQ;
    u16* w1_h = wo_l + SZQ;    u16* w1_l = w1_h + SZF;
    u16* w2_h = w1_l + SZF;    u16* w2_l = w2_h + SZF;

    cvt_qkvo<<<dim3(16, 16, 8), 256, 0, stream>>>(Wq, Wk, Wv, Wo, wqkv_h, wqkv_l, wo_h, wo_l);
    cvt_weight<<<dim3(FF/32, DD/32, LL), 256, 0, stream>>>(W1, w1_h, w1_l, DD, FF);
    cvt_weight<<<dim3(DD/32, FF/32, LL), 256, 0, stream>>>(W2, w2_h, w2_l, FF, DD);
    cvt_emb<<<(VV * DD) / 1024, 256, 0, stream>>>(emb, e16);

    embed_kernel<<<NTOK / 8, 256, 0, stream>>>(event_code, mask_code, seq_time, input_len,
                                               e16, bias_emb, sel_W, sel_b, time_W, time_b,
                                               x, a16);

    const dim3 gQKV(1536 / 64, NTOK / 128);  // (24,64) = 1536 blocks
    const dim3 gN512(DD / 64, NTOK / 128);   // (8,64)  = 512 blocks
    const dim3 gN2048(FF / 128, NTOK / 128); // (16,64) = 1024 blocks

    for (int l = 0; l < LL; ++l) {
        const u16* qkvh = wqkv_h + (long)l * 1536 * DD;
        const u16* qkvl = wqkv_l + (long)l * 1536 * DD;
        const u16* oh = wo_h + (long)l * DD * DD;  const u16* ol = wo_l + (long)l * DD * DD;
        const u16* f1h = w1_h + (long)l * DD * FF; const u16* f1l = w1_l + (long)l * DD * FF;
        const u16* f2h = w2_h + (long)l * FF * DD; const u16* f2l = w2_l + (long)l * FF * DD;

        // merged QKV projection -> bf16 q16/k16/v16
        mgemm<64,false,false,2,true><<<gQKV, 256, 0, stream>>>(
            a16, qkvh, qkvl, bq + l*DD, bk + l*DD, bv + l*DD, nullptr,
            nullptr, q16, k16, v16, 1536, DD);

        // ctx (bf16) into a16
        attn_kernel<<<NG * 8, 256, 0, stream>>>(q16, k16, v16, a16);

        // y = x + ctx@Wo + bo ; LN1 (eps 1e-3)
        mgemm<64,false,true,0,false><<<gN512, 256, 0, stream>>>(
            a16, oh, ol, bo + l*DD, nullptr, nullptr, x,
            y, nullptr, nullptr, nullptr, DD, DD);
        ln_kernel<<<NTOK, 256, 0, stream>>>(y, ln1g + l*DD, ln1b + l*DD, y, a16, 1e-3f);

        // h = relu(y@W1 + b1) -> bf16
        mgemm<128,true,false,2,false><<<gN2048, 256, 0, stream>>>(
            a16, f1h, f1l, b1 + l*FF, nullptr, nullptr, nullptr,
            nullptr, h16, nullptr, nullptr, FF, DD);
        // x = y + h@W2 + b2 ; LN2 (eps 1e-6)
        mgemm<64,false,true,0,false><<<gN512, 256, 0, stream>>>(
            h16, f2h, f2l, b2 + l*DD, nullptr, nullptr, y,
            x, nullptr, nullptr, nullptr, DD, FF);

        float* lnout = (l == LL - 1) ? (float*)d_out : x;
        ln_kernel<<<NTOK, 256, 0, stream>>>(x, ln2g + l*DD, ln2b + l*DD, lnout, a16, 1e-6f);
    }
}